// Round 15
// baseline (686.754 us; speedup 1.0000x reference)
//
#include <hip/hip_runtime.h>
#include <cmath>

#define NN 100000
#define NE 800000
#define NL 262144
#define GB 782    // ceil(NN/128): 256-col gemm blocks
#define NP1 3125  // ceil(NN/32): gemm16s blocks

typedef __attribute__((ext_vector_type(8))) short bf16x8;
typedef __attribute__((ext_vector_type(4))) float f32x4;

__device__ __forceinline__ unsigned short f2bf(float f) {
  unsigned int u = __builtin_bit_cast(unsigned int, f);
  u = (u + 0x7FFF + ((u >> 16) & 1)) >> 16;
  return (unsigned short)u;
}
__device__ __forceinline__ float bf2f(unsigned short u) {
  return __builtin_bit_cast(float, (unsigned int)u << 16);
}

// ---------------- graph prep ----------------
__global__ void k_degcnt(const int* __restrict__ dst, const float* __restrict__ w,
                         unsigned long long* __restrict__ dc) {
  int e = blockIdx.x * 256 + threadIdx.x;
  if (e < NE) {
    unsigned long long pk = (1ULL << 32) | (unsigned long long)(unsigned int)(w[e] * 8388608.0f);
    atomicAdd(&dc[dst[e]], pk);
  }
}
__global__ void k_dinv2(const unsigned long long* __restrict__ dc,
                        float* __restrict__ dinv, int* __restrict__ cnt) {
  int n = blockIdx.x * 256 + threadIdx.x;
  if (n < NN) {
    unsigned long long v = dc[n];
    cnt[n] = (int)(v >> 32);
    dinv[n] = rsqrtf((float)(unsigned int)v * (1.0f / 8388608.0f) + 1.0f);
  }
}
__global__ void k_scan1(const int* __restrict__ cnt, int* __restrict__ tsum) {
  __shared__ int s[256];
  int t = threadIdx.x;
  int base = blockIdx.x * 1024;
  int acc = 0;
  for (int i = 0; i < 4; i++) { int idx = base + t * 4 + i; if (idx < NN) acc += cnt[idx]; }
  s[t] = acc; __syncthreads();
  for (int o = 128; o > 0; o >>= 1) { if (t < o) s[t] += s[t + o]; __syncthreads(); }
  if (t == 0) tsum[blockIdx.x] = s[0];
}
__global__ void k_scan2(const int* __restrict__ tsum, int* __restrict__ toff, int nt, int* __restrict__ rowptr_end) {
  __shared__ int s[256];
  int t = threadIdx.x;
  int v = (t < nt) ? tsum[t] : 0;
  s[t] = v; __syncthreads();
  for (int o = 1; o < 256; o <<= 1) { int xv = (t >= o) ? s[t - o] : 0; __syncthreads(); s[t] += xv; __syncthreads(); }
  if (t < nt) toff[t] = s[t] - v;
  if (t == 255) *rowptr_end = s[255];
}
__global__ void k_scan3(const int* __restrict__ cnt, const int* __restrict__ toff,
                        int* __restrict__ rowptr, int* __restrict__ nxt) {
  __shared__ int s[256];
  int t = threadIdx.x;
  int base = blockIdx.x * 1024 + t * 4;
  int v[4]; int tot = 0;
  for (int i = 0; i < 4; i++) { int idx = base + i; v[i] = (idx < NN) ? cnt[idx] : 0; tot += v[i]; }
  s[t] = tot; __syncthreads();
  for (int o = 1; o < 256; o <<= 1) { int xv = (t >= o) ? s[t - o] : 0; __syncthreads(); s[t] += xv; __syncthreads(); }
  int excl = s[t] - tot + toff[blockIdx.x];
  for (int i = 0; i < 4; i++) {
    int idx = base + i;
    if (idx < NN) { rowptr[idx] = excl; nxt[idx] = excl; }
    excl += v[i];
  }
}
__global__ void k_scatter2(const int* __restrict__ src, const int* __restrict__ dst, const float* __restrict__ w,
                           const float* __restrict__ dinv, int* __restrict__ nxt,
                           int* __restrict__ esp, float* __restrict__ enp) {
  int e = blockIdx.x * 256 + threadIdx.x;
  if (e < NE) {
    int d = dst[e], s = src[e];
    int p = atomicAdd(&nxt[d], 1);
    esp[p] = s; enp[p] = dinv[s] * w[e] * dinv[d];
  }
}

// ---------------- weight convert/transpose: Wt[n*K+k] = bf16(W[k*N+n]) ----------------
__global__ void k_cvt_wT(const float* __restrict__ W, unsigned short* __restrict__ Wt, int K, int N) {
  int id = blockIdx.x * 256 + threadIdx.x;
  if (id >= K * N) return;
  int n = id / K, k = id - n * K;
  Wt[id] = f2bf(W[k * N + n]);
}
// D1W [256][128] -> Wt [256 out][128 in]: rows 0..127 = u cols, 128..255 = v cols
__global__ void k_cvt_d1(const float* __restrict__ D1W, unsigned short* __restrict__ Wt) {
  int id = blockIdx.x * 256 + threadIdx.x;
  if (id >= 256 * 128) return;
  int n = id >> 7, k = id & 127;
  float v = (n < 128) ? D1W[(size_t)k * 128 + n] : D1W[(size_t)(128 + k) * 128 + (n - 128)];
  Wt[id] = f2bf(v);
}
__global__ void k_biasuv(const float* __restrict__ D1b, float* __restrict__ buv) {
  int t = threadIdx.x;
  buv[t] = (t < 128) ? D1b[t] : 0.f;
}

// ---------------- fragment-pack ----------------
__global__ void k_pack(const unsigned short* __restrict__ Wt, unsigned short* __restrict__ P, int K, int NJ) {
  int id = blockIdx.x * 256 + threadIdx.x;
  int total = (K / 32) * NJ * 64;
  if (id >= total) return;
  int lane = id & 63, g = id >> 6;
  int j = g % NJ, s = g / NJ;
  int fr = lane & 15, fq = lane >> 4;
  uint4 v = *(const uint4*)(Wt + (size_t)(j * 16 + fr) * K + s * 32 + fq * 8);
  *(uint4*)(P + (size_t)id * 8) = v;
}

// ---------------- layer-1 agg on raw x (16 fp32 feats, 64 B rows) ----------------
__global__ __launch_bounds__(256) void k_agg16(const float* __restrict__ x,
    const int* __restrict__ esp, const float* __restrict__ enp,
    const int* __restrict__ rowptr, const float* __restrict__ dinv,
    float* __restrict__ ax) {
  const int t = threadIdx.x;
  const int lane = t & 63;
  const int g = lane >> 2, gl = lane & 3;
  const int n = blockIdx.x * 64 + (t >> 6) * 16 + g;
  if (n >= NN) return;
  const float4* x4 = (const float4*)x;
  float d = dinv[n]; float dd = d * d;
  float4 self = x4[(size_t)n * 4 + gl];
  float4 acc = make_float4(self.x * dd, self.y * dd, self.z * dd, self.w * dd);
  const int i0 = rowptr[n];
  const int dg = rowptr[n + 1] - i0;
  int sreg[4]; float wreg[4];
  #pragma unroll
  for (int k = 0; k < 4; k++) {
    int idx = gl + 4 * k;
    if (idx < dg) { sreg[k] = esp[i0 + idx]; wreg[k] = enp[i0 + idx]; }
    else { sreg[k] = 0; wreg[k] = 0.f; }
  }
  const int gbase = lane & ~3;
  const int m4 = ((dg < 16 ? dg : 16) + 3) & ~3;
  #pragma unroll 4
  for (int e = 0; e < m4; e += 4) {
    int k = e >> 2;
    int s0, s1, s2, s3; float w0, w1, w2, w3;
    switch (k) {
      case 0: s0=__shfl(sreg[0],gbase|0); s1=__shfl(sreg[0],gbase|1); s2=__shfl(sreg[0],gbase|2); s3=__shfl(sreg[0],gbase|3);
              w0=__shfl(wreg[0],gbase|0); w1=__shfl(wreg[0],gbase|1); w2=__shfl(wreg[0],gbase|2); w3=__shfl(wreg[0],gbase|3); break;
      case 1: s0=__shfl(sreg[1],gbase|0); s1=__shfl(sreg[1],gbase|1); s2=__shfl(sreg[1],gbase|2); s3=__shfl(sreg[1],gbase|3);
              w0=__shfl(wreg[1],gbase|0); w1=__shfl(wreg[1],gbase|1); w2=__shfl(wreg[1],gbase|2); w3=__shfl(wreg[1],gbase|3); break;
      case 2: s0=__shfl(sreg[2],gbase|0); s1=__shfl(sreg[2],gbase|1); s2=__shfl(sreg[2],gbase|2); s3=__shfl(sreg[2],gbase|3);
              w0=__shfl(wreg[2],gbase|0); w1=__shfl(wreg[2],gbase|1); w2=__shfl(wreg[2],gbase|2); w3=__shfl(wreg[2],gbase|3); break;
      default: s0=__shfl(sreg[3],gbase|0); s1=__shfl(sreg[3],gbase|1); s2=__shfl(sreg[3],gbase|2); s3=__shfl(sreg[3],gbase|3);
              w0=__shfl(wreg[3],gbase|0); w1=__shfl(wreg[3],gbase|1); w2=__shfl(wreg[3],gbase|2); w3=__shfl(wreg[3],gbase|3); break;
    }
    float4 r0 = x4[(size_t)s0 * 4 + gl], r1 = x4[(size_t)s1 * 4 + gl];
    float4 r2 = x4[(size_t)s2 * 4 + gl], r3 = x4[(size_t)s3 * 4 + gl];
    acc.x += w0 * r0.x + w1 * r1.x + w2 * r2.x + w3 * r3.x;
    acc.y += w0 * r0.y + w1 * r1.y + w2 * r2.y + w3 * r3.y;
    acc.z += w0 * r0.z + w1 * r1.z + w2 * r2.z + w3 * r3.z;
    acc.w += w0 * r0.w + w1 * r1.w + w2 * r2.w + w3 * r3.w;
  }
  for (int i = i0 + 16; i < i0 + dg; i++) {
    int s0 = esp[i]; float w0 = enp[i];
    float4 r0 = x4[(size_t)s0 * 4 + gl];
    acc.x += w0 * r0.x; acc.y += w0 * r0.y; acc.z += w0 * r0.z; acc.w += w0 * r0.w;
  }
  ((float4*)ax)[(size_t)n * 4 + gl] = acc;
}

// ---------------- layer-1 GEMM ----------------
__global__ __launch_bounds__(256) void k_gemm16s(const float* __restrict__ ax, const float* __restrict__ W,
                                                 const float* __restrict__ b, unsigned short* __restrict__ out,
                                                 float* __restrict__ Ps, float* __restrict__ Pq) {
  __shared__ float xs[32][17];
  int t = threadIdx.x; int row0 = blockIdx.x * 32;
  for (int i = t; i < 512; i += 256) {
    int r = i >> 4, c = i & 15; int row = row0 + r;
    xs[r][c] = (row < NN) ? ax[(size_t)row * 16 + c] : 0.f;
  }
  float w[16];
  #pragma unroll
  for (int k = 0; k < 16; k++) w[k] = W[k * 256 + t];
  float bt = b[t];
  __syncthreads();
  float s_ = 0.f, q_ = 0.f;
  for (int r = 0; r < 32; r++) {
    int row = row0 + r; if (row >= NN) break;
    float acc = bt;
    #pragma unroll
    for (int k = 0; k < 16; k++) acc += xs[r][k] * w[k];
    out[(size_t)row * 256 + t] = f2bf(acc);
    s_ += acc; q_ += acc * acc;
  }
  Ps[(size_t)blockIdx.x * 256 + t] = s_;
  Pq[(size_t)blockIdx.x * 256 + t] = q_;
}

// ---------------- bf16 row load helper ----------------
template <int FPL>
__device__ __forceinline__ void ldF(const unsigned short* p, float* f) {
  if constexpr (FPL == 8) {
    uint4 v = *(const uint4*)p;
    unsigned int u[4] = {v.x, v.y, v.z, v.w};
    #pragma unroll
    for (int i = 0; i < 4; i++) {
      f[2 * i] = bf2f((unsigned short)(u[i] & 0xFFFF));
      f[2 * i + 1] = bf2f((unsigned short)(u[i] >> 16));
    }
  } else {
    ushort4 v = *(const ushort4*)p;
    f[0] = bf2f(v.x); f[1] = bf2f(v.y); f[2] = bf2f(v.z); f[3] = bf2f(v.w);
  }
}

// ---------------- FUSED agg + MFMA GEMM ----------------
// Gather phase: 16 half-waves aggregate 128 node rows (BN+ReLU / bias on gathered
// values) directly into LDS as bf16. MFMA phase: v12 (B in regs, 8 waves x CPW cols).
template <int KDIM, int NCOLS, bool STATS, bool BNG, bool BIASG>
__global__ __launch_bounds__(512) void k_fused(
    const unsigned short* __restrict__ src,
    const int* __restrict__ esp, const float* __restrict__ enp,
    const int* __restrict__ rowptr, const float* __restrict__ dinv,
    const unsigned short* __restrict__ Wp,
    const float* __restrict__ biasM, const float* __restrict__ bnsc, const float* __restrict__ bnsh,
    const float* __restrict__ biasG,
    unsigned short* __restrict__ C, float* __restrict__ Ps, float* __restrict__ Pq) {
  constexpr int FPL = KDIM / 32;
  constexpr int CPW = NCOLS / 128;
  constexpr int KS = KDIM / 32;
  constexpr int LDA = KDIM + 8;
  __shared__ unsigned short S[128 * LDA];
  const int t = threadIdx.x;
  const int lane = t & 63, w = t >> 6, fr = lane & 15, fq = lane >> 4;
  const int row0 = blockIdx.x * 128;
  // ---- gather phase ----
  {
    const int lg = lane & 31;
    const int srcb = lane & 32;
    const int hw = t >> 5;             // 0..15 half-waves
    const int f0 = lg * FPL;
    float scR[FPL], shR[FPL], bgR[FPL];
    if constexpr (BNG) {
      #pragma unroll
      for (int j = 0; j < FPL; j++) { scR[j] = bnsc[f0 + j]; shR[j] = bnsh[f0 + j]; }
    }
    if constexpr (BIASG) {
      #pragma unroll
      for (int j = 0; j < FPL; j++) bgR[j] = biasG[f0 + j];
    }
    auto xf = [&](float v, int j) -> float {
      if constexpr (BNG) return fmaxf(v * scR[j] + shR[j], 0.f);
      else return v;
    };
    for (int pass = 0; pass < 8; pass++) {
      const int r = pass * 16 + hw;
      const int n = row0 + r;
      float acc[FPL];
      #pragma unroll
      for (int j = 0; j < FPL; j++) acc[j] = 0.f;
      if (n < NN) {
        float d = dinv[n]; float dd = d * d;
        {
          float sv[FPL];
          ldF<FPL>(src + (size_t)n * KDIM + f0, sv);
          #pragma unroll
          for (int j = 0; j < FPL; j++) acc[j] = xf(sv[j], j) * dd + (BIASG ? bgR[j] : 0.f);
        }
        const int i0 = rowptr[n];
        const int dg = rowptr[n + 1] - i0;
        int sreg = 0; float wreg = 0.f;
        if (lg < dg) { sreg = esp[i0 + lg]; wreg = enp[i0 + lg]; }
        const int m = (dg < 32) ? dg : 32;
        int e = 0;
        for (; e + 4 <= m; e += 4) {
          int s0 = __shfl(sreg, srcb | e), s1 = __shfl(sreg, srcb | (e + 1));
          int s2 = __shfl(sreg, srcb | (e + 2)), s3 = __shfl(sreg, srcb | (e + 3));
          float w0 = __shfl(wreg, srcb | e), w1 = __shfl(wreg, srcb | (e + 1));
          float w2 = __shfl(wreg, srcb | (e + 2)), w3 = __shfl(wreg, srcb | (e + 3));
          float r0[FPL], r1[FPL], r2[FPL], r3[FPL];
          ldF<FPL>(src + (size_t)s0 * KDIM + f0, r0);
          ldF<FPL>(src + (size_t)s1 * KDIM + f0, r1);
          ldF<FPL>(src + (size_t)s2 * KDIM + f0, r2);
          ldF<FPL>(src + (size_t)s3 * KDIM + f0, r3);
          #pragma unroll
          for (int j = 0; j < FPL; j++)
            acc[j] += w0 * xf(r0[j], j) + w1 * xf(r1[j], j) + w2 * xf(r2[j], j) + w3 * xf(r3[j], j);
        }
        for (; e < m; e++) {
          int s0 = __shfl(sreg, srcb | e); float w0 = __shfl(wreg, srcb | e);
          float r0[FPL];
          ldF<FPL>(src + (size_t)s0 * KDIM + f0, r0);
          #pragma unroll
          for (int j = 0; j < FPL; j++) acc[j] += w0 * xf(r0[j], j);
        }
        for (int i = i0 + 32; i < i0 + dg; i++) {
          int s0 = esp[i]; float w0 = enp[i];
          float r0[FPL];
          ldF<FPL>(src + (size_t)s0 * KDIM + f0, r0);
          #pragma unroll
          for (int j = 0; j < FPL; j++) acc[j] += w0 * xf(r0[j], j);
        }
      }
      // pack bf16 -> LDS
      if constexpr (FPL == 8) {
        unsigned int o[4];
        #pragma unroll
        for (int i = 0; i < 4; i++)
          o[i] = (unsigned int)f2bf(acc[2 * i]) | ((unsigned int)f2bf(acc[2 * i + 1]) << 16);
        *(uint4*)(S + r * LDA + f0) = make_uint4(o[0], o[1], o[2], o[3]);
      } else {
        ushort4 o; o.x = f2bf(acc[0]); o.y = f2bf(acc[1]); o.z = f2bf(acc[2]); o.w = f2bf(acc[3]);
        *(ushort4*)(S + r * LDA + f0) = o;
      }
    }
  }
  // ---- B preload (overlaps barrier) ----
  bf16x8 B[CPW][KS];
  #pragma unroll
  for (int c = 0; c < CPW; c++)
    #pragma unroll
    for (int s = 0; s < KS; s++)
      B[c][s] = *(const bf16x8*)(Wp + ((size_t)(s * (NCOLS / 16) + (w * CPW + c)) * 64 + lane) * 8);
  __syncthreads();
  // ---- MFMA phase ----
  f32x4 acc[8][CPW] = {};
  #pragma unroll
  for (int r = 0; r < 8; r++) {
    #pragma unroll
    for (int s = 0; s < KS; s++) {
      bf16x8 a = *(const bf16x8*)(S + (r * 16 + fr) * LDA + s * 32 + fq * 8);
      #pragma unroll
      for (int c = 0; c < CPW; c++)
        acc[r][c] = __builtin_amdgcn_mfma_f32_16x16x32_bf16(a, B[c][s], acc[r][c], 0, 0, 0);
    }
  }
  #pragma unroll
  for (int c = 0; c < CPW; c++) {
    const int col = w * (16 * CPW) + c * 16 + fr;
    float bj = biasM[col];
    float s_ = 0.f, q_ = 0.f;
    #pragma unroll
    for (int r = 0; r < 8; r++) {
      #pragma unroll
      for (int rr = 0; rr < 4; rr++) {
        int row = row0 + r * 16 + fq * 4 + rr;
        if (row < NN) {
          float cv = acc[r][c][rr] + bj;
          C[(size_t)row * NCOLS + col] = f2bf(cv);
          if (STATS) { s_ += cv; q_ += cv * cv; }
        }
      }
    }
    if (STATS) {
      s_ += __shfl_xor(s_, 16); q_ += __shfl_xor(q_, 16);
      s_ += __shfl_xor(s_, 32); q_ += __shfl_xor(q_, 32);
      if (fq == 0) {
        Ps[(size_t)blockIdx.x * 256 + col] = s_;
        Pq[(size_t)blockIdx.x * 256 + col] = q_;
      }
    }
  }
}

// ---------------- MFMA GEMM v12 (plain, BN-on-A variant for layer 4a) ----------------
template <int KDIM, int NCOLS, bool STATS, bool BNA>
__global__ __launch_bounds__(512) void k_gemm_v12(
    const unsigned short* __restrict__ A, const unsigned short* __restrict__ Wp,
    const float* __restrict__ bias, const float* __restrict__ bnsc, const float* __restrict__ bnsh,
    unsigned short* __restrict__ C, float* __restrict__ Ps, float* __restrict__ Pq) {
  constexpr int CPW = NCOLS / 128;
  constexpr int KS = KDIM / 32;
  constexpr int LDA = KDIM + 8;
  constexpr int NU4 = KDIM / 32;
  __shared__ unsigned short S[128 * LDA];
  __shared__ float sc[BNA ? KDIM : 1], sh[BNA ? KDIM : 1];
  const int t = threadIdx.x;
  const int lane = t & 63, w = t >> 6, fr = lane & 15, fq = lane >> 4;
  const int row0 = blockIdx.x * 128;
  if (BNA) {
    if (t < KDIM) { sc[t] = bnsc[t]; sh[t] = bnsh[t]; }
    __syncthreads();
  }
  bf16x8 B[CPW][KS];
  #pragma unroll
  for (int c = 0; c < CPW; c++)
    #pragma unroll
    for (int s = 0; s < KS; s++)
      B[c][s] = *(const bf16x8*)(Wp + ((size_t)(s * (NCOLS / 16) + (w * CPW + c)) * 64 + lane) * 8);
  {
    int r = t >> 2, q = t & 3;
    int row = row0 + r;
    uint4* dst = (uint4*)(S + r * LDA + q * (KDIM / 4));
    if (row < NN) {
      const uint4* src = (const uint4*)(A + (size_t)row * KDIM + q * (KDIM / 4));
      #pragma unroll
      for (int i = 0; i < NU4; i++) {
        uint4 v = src[i];
        if (BNA) {
          unsigned int u[4] = {v.x, v.y, v.z, v.w};
          #pragma unroll
          for (int p = 0; p < 4; p++) {
            int colb = q * (KDIM / 4) + i * 8 + p * 2;
            float lo = fmaxf(bf2f((unsigned short)(u[p] & 0xFFFF)) * sc[colb] + sh[colb], 0.f);
            float hi = fmaxf(bf2f((unsigned short)(u[p] >> 16)) * sc[colb + 1] + sh[colb + 1], 0.f);
            u[p] = (unsigned int)f2bf(lo) | ((unsigned int)f2bf(hi) << 16);
          }
          v = make_uint4(u[0], u[1], u[2], u[3]);
        }
        dst[i] = v;
      }
    } else {
      #pragma unroll
      for (int i = 0; i < NU4; i++) dst[i] = make_uint4(0, 0, 0, 0);
    }
  }
  __syncthreads();
  f32x4 acc[8][CPW] = {};
  #pragma unroll
  for (int r = 0; r < 8; r++) {
    #pragma unroll
    for (int s = 0; s < KS; s++) {
      bf16x8 a = *(const bf16x8*)(S + (r * 16 + fr) * LDA + s * 32 + fq * 8);
      #pragma unroll
      for (int c = 0; c < CPW; c++)
        acc[r][c] = __builtin_amdgcn_mfma_f32_16x16x32_bf16(a, B[c][s], acc[r][c], 0, 0, 0);
    }
  }
  #pragma unroll
  for (int c = 0; c < CPW; c++) {
    const int col = w * (16 * CPW) + c * 16 + fr;
    float bj = bias[col];
    float s_ = 0.f, q_ = 0.f;
    #pragma unroll
    for (int r = 0; r < 8; r++) {
      #pragma unroll
      for (int rr = 0; rr < 4; rr++) {
        int row = row0 + r * 16 + fq * 4 + rr;
        if (row < NN) {
          float cv = acc[r][c][rr] + bj;
          C[(size_t)row * NCOLS + col] = f2bf(cv);
          if (STATS) { s_ += cv; q_ += cv * cv; }
        }
      }
    }
    if (STATS) {
      s_ += __shfl_xor(s_, 16); q_ += __shfl_xor(q_, 16);
      s_ += __shfl_xor(s_, 32); q_ += __shfl_xor(q_, 32);
      if (fq == 0) {
        Ps[(size_t)blockIdx.x * 256 + col] = s_;
        Pq[(size_t)blockIdx.x * 256 + col] = q_;
      }
    }
  }
}

// ---------------- reduce block partials -> scale/shift ----------------
__global__ __launch_bounds__(256) void k_bnred(const float* __restrict__ Ps, const float* __restrict__ Pq,
                                               const float* __restrict__ g, const float* __restrict__ be,
                                               float* __restrict__ scale, float* __restrict__ shift, int np) {
  __shared__ float Ss[256], Sq[256];
  const int f = blockIdx.x;
  const int t = threadIdx.x;
  float s = 0.f, q = 0.f;
  for (int p = t; p < np; p += 256) { s += Ps[(size_t)p * 256 + f]; q += Pq[(size_t)p * 256 + f]; }
  Ss[t] = s; Sq[t] = q;
  __syncthreads();
  for (int o = 128; o > 0; o >>= 1) { if (t < o) { Ss[t] += Ss[t + o]; Sq[t] += Sq[t + o]; } __syncthreads(); }
  if (t == 0) {
    float m = Ss[0] * (1.f / NN);
    float v = Sq[0] * (1.f / NN) - m * m;
    float sc = g[f] * rsqrtf(v + 1e-5f);
    scale[f] = sc; shift[f] = be[f] - m * sc;
  }
}

// ---------------- fused decoder ----------------
__global__ __launch_bounds__(256) void k_decoder3(
    const unsigned short* __restrict__ uv,
    const int* __restrict__ l0, const int* __restrict__ l1,
    const unsigned short* __restrict__ W2p, const float* __restrict__ D2b,
    const float* __restrict__ D3W, const float* __restrict__ D3b,
    float* __restrict__ out) {
  __shared__ unsigned short S[128 * 136];
  __shared__ int ei0[128], ei1[128];
  const int t = threadIdx.x;
  const int base = blockIdx.x * 128;
  if (t < 128) ei0[t] = l0[base + t];
  else ei1[t - 128] = l1[base + t - 128];
  __syncthreads();
  {
    int e = t >> 1, h = t & 1;
    const uint4* pu = (const uint4*)(uv + (size_t)ei0[e] * 256 + h * 64);
    const uint4* pv = (const uint4*)(uv + (size_t)ei1[e] * 256 + 128 + h * 64);
    uint4* dst = (uint4*)(S + e * 136 + h * 64);
    #pragma unroll
    for (int i = 0; i < 8; i++) {
      uint4 a = pu[i], b = pv[i];
      unsigned int ia[4] = {a.x, a.y, a.z, a.w};
      unsigned int ib[4] = {b.x, b.y, b.z, b.w};
      unsigned int o[4];
      #pragma unroll
      for (int p = 0; p < 4; p++) {
        float lo = fmaxf(bf2f((unsigned short)(ia[p] & 0xFFFF)) + bf2f((unsigned short)(ib[p] & 0xFFFF)), 0.f);
        float hi = fmaxf(bf2f((unsigned short)(ia[p] >> 16)) + bf2f((unsigned short)(ib[p] >> 16)), 0.f);
        o[p] = (unsigned int)f2bf(lo) | ((unsigned int)f2bf(hi) << 16);
      }
      dst[i] = make_uint4(o[0], o[1], o[2], o[3]);
    }
  }
  __syncthreads();
  const int lane = t & 63, w = t >> 6, fr = lane & 15, fq = lane >> 4;
  f32x4 acc2[2][8] = {};
  #pragma unroll
  for (int s = 0; s < 4; s++) {
    bf16x8 a0 = *(const bf16x8*)(S + (w * 32 + fr) * 136 + s * 32 + fq * 8);
    bf16x8 a1 = *(const bf16x8*)(S + (w * 32 + 16 + fr) * 136 + s * 32 + fq * 8);
    #pragma unroll
    for (int j = 0; j < 8; j++) {
      bf16x8 bw = *(const bf16x8*)(W2p + ((size_t)(s * 8 + j) * 64 + lane) * 8);
      acc2[0][j] = __builtin_amdgcn_mfma_f32_16x16x32_bf16(a0, bw, acc2[0][j], 0, 0, 0);
      acc2[1][j] = __builtin_amdgcn_mfma_f32_16x16x32_bf16(a1, bw, acc2[1][j], 0, 0, 0);
    }
  }
  float b2v[8], w3v[8];
  #pragma unroll
  for (int j = 0; j < 8; j++) { b2v[j] = D2b[j * 16 + fr]; w3v[j] = D3W[j * 16 + fr]; }
  float d3b = D3b[0];
  #pragma unroll
  for (int f = 0; f < 2; f++) {
    float p[4] = {0.f, 0.f, 0.f, 0.f};
    #pragma unroll
    for (int j = 0; j < 8; j++)
      #pragma unroll
      for (int r = 0; r < 4; r++)
        p[r] += fmaxf(acc2[f][j][r] + b2v[j], 0.f) * w3v[j];
    #pragma unroll
    for (int r = 0; r < 4; r++) {
      p[r] += __shfl_xor(p[r], 1);
      p[r] += __shfl_xor(p[r], 2);
      p[r] += __shfl_xor(p[r], 4);
      p[r] += __shfl_xor(p[r], 8);
      if (fr == 0) out[base + w * 32 + f * 16 + fq * 4 + r] = 1.f / (1.f + expf(-(p[r] + d3b)));
    }
  }
}

// ---------------- host ----------------
extern "C" void kernel_launch(void* const* d_in, const int* in_sizes, int n_in,
                              void* d_out, int out_size, void* d_ws, size_t ws_size,
                              hipStream_t stream) {
  const float* x = (const float*)d_in[0];
  const int* ei = (const int*)d_in[1];
  const int* esrc = ei; const int* edst = ei + NE;
  const float* ew = (const float*)d_in[2];
  const int* eli = (const int*)d_in[3];
  const int* l0 = eli; const int* l1 = eli + NL;
  const float* W1 = (const float*)d_in[4],  *b1 = (const float*)d_in[5];
  const float* g1 = (const float*)d_in[6],  *be1 = (const float*)d_in[7];
  const float* W2 = (const float*)d_in[8],  *b2 = (const float*)d_in[9];
  const float* g2 = (const float*)d_in[10], *be2 = (const float*)d_in[11];
  const float* W3 = (const float*)d_in[12], *b3 = (const float*)d_in[13];
  const float* g3 = (const float*)d_in[14], *be3 = (const float*)d_in[15];
  const float* W4 = (const float*)d_in[16], *b4 = (const float*)d_in[17];
  const float* D1W = (const float*)d_in[18], *D1b = (const float*)d_in[19];
  const float* D2W = (const float*)d_in[20], *D2b = (const float*)d_in[21];
  const float* D3W = (const float*)d_in[22], *D3b = (const float*)d_in[23];
  float* out = (float*)d_out;

  float* wf = (float*)d_ws;
  size_t off = 0;
  auto A = [&](size_t n) { float* p = wf + off; off += (n + 63) & ~(size_t)63; return p; };
  float* dinv = A(NN);
  float* enp = A(NE);
  float* scale = A(256);
  float* shift = A(256);
  float* buv = A(256);
  float* zero128 = A(128);
  float* Ps = A((size_t)NP1 * 256);
  float* Pq = A((size_t)NP1 * 256);
  float* axf = A((size_t)NN * 16);
  unsigned long long* dc = (unsigned long long*)A(2 * (size_t)NN);
  int* cnt = (int*)A(NN);
  int* rowptr = (int*)A(NN + 1);
  int* nxt = (int*)A(NN);
  int* esp = (int*)A(NE);
  int* tsum = (int*)A(256);
  int* toff = (int*)A(256);
  unsigned short* hbA = (unsigned short*)A((size_t)NN * 128);
  unsigned short* hbB = (unsigned short*)A((size_t)NN * 128);
  unsigned short* uv  = (unsigned short*)A((size_t)NN * 128);
  unsigned short* wt2 = (unsigned short*)A(256 * 128);
  unsigned short* wt3 = (unsigned short*)A(256 * 128);
  unsigned short* wt4 = (unsigned short*)A(128 * 128);
  unsigned short* wtD1 = (unsigned short*)A(128 * 128);
  unsigned short* w2t = (unsigned short*)A(64 * 128);
  unsigned short* wp2 = (unsigned short*)A(256 * 128);
  unsigned short* wp3 = (unsigned short*)A(256 * 128);
  unsigned short* wp4 = (unsigned short*)A(128 * 128);
  unsigned short* wpD1 = (unsigned short*)A(128 * 128);
  unsigned short* w2p = (unsigned short*)A(64 * 128);

  const int EB = (NE + 255) / 256;
  const int NB = (NN + 255) / 256;
  const int ST = (NN + 1023) / 1024;
  const int AG16 = (NN + 63) / 64;

  // graph prep
  hipMemsetAsync(dc, 0, (size_t)NN * 8, stream);
  hipMemsetAsync(zero128, 0, 128 * sizeof(float), stream);
  k_degcnt<<<EB, 256, 0, stream>>>(edst, ew, dc);
  k_dinv2<<<NB, 256, 0, stream>>>(dc, dinv, cnt);
  k_scan1<<<ST, 256, 0, stream>>>(cnt, tsum);
  k_scan2<<<1, 256, 0, stream>>>(tsum, toff, ST, rowptr + NN);
  k_scan3<<<ST, 256, 0, stream>>>(cnt, toff, rowptr, nxt);
  k_scatter2<<<EB, 256, 0, stream>>>(esrc, edst, ew, dinv, nxt, esp, enp);

  // weight conversions + fragment packing
  k_cvt_wT<<<(256 * 256 + 255) / 256, 256, 0, stream>>>(W2, wt2, 256, 256);
  k_cvt_wT<<<(256 * 256 + 255) / 256, 256, 0, stream>>>(W3, wt3, 256, 256);
  k_cvt_wT<<<(256 * 128 + 255) / 256, 256, 0, stream>>>(W4, wt4, 256, 128);
  k_cvt_d1<<<(256 * 128 + 255) / 256, 256, 0, stream>>>(D1W, wtD1);
  k_cvt_wT<<<(128 * 128 + 255) / 256, 256, 0, stream>>>(D2W, w2t, 128, 128);
  k_biasuv<<<1, 256, 0, stream>>>(D1b, buv);
  k_pack<<<32, 256, 0, stream>>>(wt2, wp2, 256, 16);
  k_pack<<<32, 256, 0, stream>>>(wt3, wp3, 256, 16);
  k_pack<<<16, 256, 0, stream>>>(wt4, wp4, 256, 8);
  k_pack<<<16, 256, 0, stream>>>(wtD1, wpD1, 128, 16);
  k_pack<<<8, 256, 0, stream>>>(w2t, w2p, 128, 8);

  // layer 1: ax = agg(x) [fp32,16] ; h1 = ax@W1 + b1 (+stats)
  k_agg16<<<AG16, 256, 0, stream>>>(x, esp, enp, rowptr, dinv, axf);
  k_gemm16s<<<NP1, 256, 0, stream>>>(axf, W1, b1, hbB, Ps, Pq);
  k_bnred<<<256, 256, 0, stream>>>(Ps, Pq, g1, be1, scale, shift, NP1);

  // layer 2 (fused): h2 = agg(relu(BN1(h1)))@W2 + b2 (+stats)
  k_fused<256, 256, true, true, false><<<GB, 512, 0, stream>>>(
      hbB, esp, enp, rowptr, dinv, wp2, b2, scale, shift, nullptr, hbA, Ps, Pq);
  k_bnred<<<256, 256, 0, stream>>>(Ps, Pq, g2, be2, scale, shift, GB);

  // layer 3 (fused)
  k_fused<256, 256, true, true, false><<<GB, 512, 0, stream>>>(
      hbA, esp, enp, rowptr, dinv, wp3, b3, scale, shift, nullptr, hbB, Ps, Pq);
  k_bnred<<<256, 256, 0, stream>>>(Ps, Pq, g3, be3, scale, shift, GB);

  // layer 4a: t = relu(BN3(h3))@W4 [bf16,128]
  k_gemm_v12<256, 128, false, true><<<GB, 512, 0, stream>>>(hbB, wp4, zero128, scale, shift, hbA, nullptr, nullptr);
  // layer 4b (fused): uv = (agg(t)+b4)@[D1Wu|D1Wv] + buv
  k_fused<128, 256, false, false, true><<<GB, 512, 0, stream>>>(
      hbA, esp, enp, rowptr, dinv, wpD1, buv, nullptr, nullptr, b4, uv, nullptr, nullptr);

  // decoder layers 2-3
  k_decoder3<<<NL / 128, 256, 0, stream>>>(uv, l0, l1, w2p, D2b, D3W, D3b, out);
}

// Round 16
// 607.246 us; speedup vs baseline: 1.1309x; 1.1309x over previous
//
#include <hip/hip_runtime.h>
#include <cmath>

#define NN 100000
#define NE 800000
#define NL 262144
#define GB 782    // ceil(NN/128): 256-col gemm blocks
#define NP1 3125  // ceil(NN/32): gemm16s blocks

typedef __attribute__((ext_vector_type(8))) short bf16x8;
typedef __attribute__((ext_vector_type(4))) float f32x4;

__device__ __forceinline__ unsigned short f2bf(float f) {
  unsigned int u = __builtin_bit_cast(unsigned int, f);
  u = (u + 0x7FFF + ((u >> 16) & 1)) >> 16;
  return (unsigned short)u;
}
__device__ __forceinline__ float bf2f(unsigned short u) {
  return __builtin_bit_cast(float, (unsigned int)u << 16);
}
__device__ __forceinline__ void unpk(unsigned long long v, int& s, float& w) {
  s = (int)(unsigned int)v;
  w = __builtin_bit_cast(float, (unsigned int)(v >> 32));
}

// ---------------- graph prep ----------------
__global__ void k_degcnt(const int* __restrict__ dst, const float* __restrict__ w,
                         unsigned long long* __restrict__ dc) {
  int e = blockIdx.x * 256 + threadIdx.x;
  if (e < NE) {
    unsigned long long pk = (1ULL << 32) | (unsigned long long)(unsigned int)(w[e] * 8388608.0f);
    atomicAdd(&dc[dst[e]], pk);
  }
}
__global__ void k_dinv2(const unsigned long long* __restrict__ dc,
                        float* __restrict__ dinv, int* __restrict__ cnt) {
  int n = blockIdx.x * 256 + threadIdx.x;
  if (n < NN) {
    unsigned long long v = dc[n];
    cnt[n] = (int)(v >> 32);
    dinv[n] = rsqrtf((float)(unsigned int)v * (1.0f / 8388608.0f) + 1.0f);
  }
}
__global__ void k_scan1(const int* __restrict__ cnt, int* __restrict__ tsum) {
  __shared__ int s[256];
  int t = threadIdx.x;
  int base = blockIdx.x * 1024;
  int acc = 0;
  for (int i = 0; i < 4; i++) { int idx = base + t * 4 + i; if (idx < NN) acc += cnt[idx]; }
  s[t] = acc; __syncthreads();
  for (int o = 128; o > 0; o >>= 1) { if (t < o) s[t] += s[t + o]; __syncthreads(); }
  if (t == 0) tsum[blockIdx.x] = s[0];
}
__global__ void k_scan2(const int* __restrict__ tsum, int* __restrict__ toff, int nt, int* __restrict__ rowptr_end) {
  __shared__ int s[256];
  int t = threadIdx.x;
  int v = (t < nt) ? tsum[t] : 0;
  s[t] = v; __syncthreads();
  for (int o = 1; o < 256; o <<= 1) { int xv = (t >= o) ? s[t - o] : 0; __syncthreads(); s[t] += xv; __syncthreads(); }
  if (t < nt) toff[t] = s[t] - v;
  if (t == 255) *rowptr_end = s[255];
}
__global__ void k_scan3(const int* __restrict__ cnt, const int* __restrict__ toff,
                        int* __restrict__ rowptr, int* __restrict__ nxt) {
  __shared__ int s[256];
  int t = threadIdx.x;
  int base = blockIdx.x * 1024 + t * 4;
  int v[4]; int tot = 0;
  for (int i = 0; i < 4; i++) { int idx = base + i; v[i] = (idx < NN) ? cnt[idx] : 0; tot += v[i]; }
  s[t] = tot; __syncthreads();
  for (int o = 1; o < 256; o <<= 1) { int xv = (t >= o) ? s[t - o] : 0; __syncthreads(); s[t] += xv; __syncthreads(); }
  int excl = s[t] - tot + toff[blockIdx.x];
  for (int i = 0; i < 4; i++) {
    int idx = base + i;
    if (idx < NN) { rowptr[idx] = excl; nxt[idx] = excl; }
    excl += v[i];
  }
}
// scatter: one packed 8B store per edge (src | w_bits<<32), enorm fused
__global__ void k_scatter2(const int* __restrict__ src, const int* __restrict__ dst, const float* __restrict__ w,
                           const float* __restrict__ dinv, int* __restrict__ nxt,
                           unsigned long long* __restrict__ edg) {
  int e = blockIdx.x * 256 + threadIdx.x;
  if (e < NE) {
    int d = dst[e], s = src[e];
    int p = atomicAdd(&nxt[d], 1);
    float en = dinv[s] * w[e] * dinv[d];
    edg[p] = ((unsigned long long)__builtin_bit_cast(unsigned int, en) << 32) | (unsigned int)s;
  }
}

// ---------------- weight convert/transpose: Wt[n*K+k] = bf16(W[k*N+n]) ----------------
__global__ void k_cvt_wT(const float* __restrict__ W, unsigned short* __restrict__ Wt, int K, int N) {
  int id = blockIdx.x * 256 + threadIdx.x;
  if (id >= K * N) return;
  int n = id / K, k = id - n * K;
  Wt[id] = f2bf(W[k * N + n]);
}
__global__ void k_cvt_d1(const float* __restrict__ D1W, unsigned short* __restrict__ Wt) {
  int id = blockIdx.x * 256 + threadIdx.x;
  if (id >= 256 * 128) return;
  int n = id >> 7, k = id & 127;
  float v = (n < 128) ? D1W[(size_t)k * 128 + n] : D1W[(size_t)(128 + k) * 128 + (n - 128)];
  Wt[id] = f2bf(v);
}
__global__ void k_biasuv(const float* __restrict__ D1b, float* __restrict__ buv) {
  int t = threadIdx.x;
  buv[t] = (t < 128) ? D1b[t] : 0.f;
}

// ---------------- fragment-pack ----------------
__global__ void k_pack(const unsigned short* __restrict__ Wt, unsigned short* __restrict__ P, int K, int NJ) {
  int id = blockIdx.x * 256 + threadIdx.x;
  int total = (K / 32) * NJ * 64;
  if (id >= total) return;
  int lane = id & 63, g = id >> 6;
  int j = g % NJ, s = g / NJ;
  int fr = lane & 15, fq = lane >> 4;
  uint4 v = *(const uint4*)(Wt + (size_t)(j * 16 + fr) * K + s * 32 + fq * 8);
  *(uint4*)(P + (size_t)id * 8) = v;
}

// ---------------- layer-1 agg on raw x (16 fp32 feats) ----------------
__global__ __launch_bounds__(256) void k_agg16(const float* __restrict__ x,
    const unsigned long long* __restrict__ edg,
    const int* __restrict__ rowptr, const float* __restrict__ dinv,
    float* __restrict__ ax) {
  const int t = threadIdx.x;
  const int lane = t & 63;
  const int g = lane >> 2, gl = lane & 3;
  const int n = blockIdx.x * 64 + (t >> 6) * 16 + g;
  if (n >= NN) return;
  const float4* x4 = (const float4*)x;
  float d = dinv[n]; float dd = d * d;
  float4 self = x4[(size_t)n * 4 + gl];
  float4 acc = make_float4(self.x * dd, self.y * dd, self.z * dd, self.w * dd);
  const int i0 = rowptr[n];
  const int dg = rowptr[n + 1] - i0;
  int sreg[4]; float wreg[4];
  #pragma unroll
  for (int k = 0; k < 4; k++) {
    int idx = gl + 4 * k;
    if (idx < dg) unpk(edg[i0 + idx], sreg[k], wreg[k]);
    else { sreg[k] = 0; wreg[k] = 0.f; }
  }
  const int gbase = lane & ~3;
  const int m4 = ((dg < 16 ? dg : 16) + 3) & ~3;
  #pragma unroll 4
  for (int e = 0; e < m4; e += 4) {
    int k = e >> 2;
    int s0, s1, s2, s3; float w0, w1, w2, w3;
    switch (k) {
      case 0: s0=__shfl(sreg[0],gbase|0); s1=__shfl(sreg[0],gbase|1); s2=__shfl(sreg[0],gbase|2); s3=__shfl(sreg[0],gbase|3);
              w0=__shfl(wreg[0],gbase|0); w1=__shfl(wreg[0],gbase|1); w2=__shfl(wreg[0],gbase|2); w3=__shfl(wreg[0],gbase|3); break;
      case 1: s0=__shfl(sreg[1],gbase|0); s1=__shfl(sreg[1],gbase|1); s2=__shfl(sreg[1],gbase|2); s3=__shfl(sreg[1],gbase|3);
              w0=__shfl(wreg[1],gbase|0); w1=__shfl(wreg[1],gbase|1); w2=__shfl(wreg[1],gbase|2); w3=__shfl(wreg[1],gbase|3); break;
      case 2: s0=__shfl(sreg[2],gbase|0); s1=__shfl(sreg[2],gbase|1); s2=__shfl(sreg[2],gbase|2); s3=__shfl(sreg[2],gbase|3);
              w0=__shfl(wreg[2],gbase|0); w1=__shfl(wreg[2],gbase|1); w2=__shfl(wreg[2],gbase|2); w3=__shfl(wreg[2],gbase|3); break;
      default: s0=__shfl(sreg[3],gbase|0); s1=__shfl(sreg[3],gbase|1); s2=__shfl(sreg[3],gbase|2); s3=__shfl(sreg[3],gbase|3);
              w0=__shfl(wreg[3],gbase|0); w1=__shfl(wreg[3],gbase|1); w2=__shfl(wreg[3],gbase|2); w3=__shfl(wreg[3],gbase|3); break;
    }
    float4 r0 = x4[(size_t)s0 * 4 + gl], r1 = x4[(size_t)s1 * 4 + gl];
    float4 r2 = x4[(size_t)s2 * 4 + gl], r3 = x4[(size_t)s3 * 4 + gl];
    acc.x += w0 * r0.x + w1 * r1.x + w2 * r2.x + w3 * r3.x;
    acc.y += w0 * r0.y + w1 * r1.y + w2 * r2.y + w3 * r3.y;
    acc.z += w0 * r0.z + w1 * r1.z + w2 * r2.z + w3 * r3.z;
    acc.w += w0 * r0.w + w1 * r1.w + w2 * r2.w + w3 * r3.w;
  }
  for (int i = i0 + 16; i < i0 + dg; i++) {
    int s0; float w0; unpk(edg[i], s0, w0);
    float4 r0 = x4[(size_t)s0 * 4 + gl];
    acc.x += w0 * r0.x; acc.y += w0 * r0.y; acc.z += w0 * r0.z; acc.w += w0 * r0.w;
  }
  ((float4*)ax)[(size_t)n * 4 + gl] = acc;
}

// ---------------- layer-1 GEMM ----------------
__global__ __launch_bounds__(256) void k_gemm16s(const float* __restrict__ ax, const float* __restrict__ W,
                                                 const float* __restrict__ b, unsigned short* __restrict__ out,
                                                 float* __restrict__ Ps, float* __restrict__ Pq) {
  __shared__ float xs[32][17];
  int t = threadIdx.x; int row0 = blockIdx.x * 32;
  for (int i = t; i < 512; i += 256) {
    int r = i >> 4, c = i & 15; int row = row0 + r;
    xs[r][c] = (row < NN) ? ax[(size_t)row * 16 + c] : 0.f;
  }
  float w[16];
  #pragma unroll
  for (int k = 0; k < 16; k++) w[k] = W[k * 256 + t];
  float bt = b[t];
  __syncthreads();
  float s_ = 0.f, q_ = 0.f;
  for (int r = 0; r < 32; r++) {
    int row = row0 + r; if (row >= NN) break;
    float acc = bt;
    #pragma unroll
    for (int k = 0; k < 16; k++) acc += xs[r][k] * w[k];
    out[(size_t)row * 256 + t] = f2bf(acc);
    s_ += acc; q_ += acc * acc;
  }
  Ps[(size_t)blockIdx.x * 256 + t] = s_;
  Pq[(size_t)blockIdx.x * 256 + t] = q_;
}

// ---------------- MFMA GEMM v12: B in registers, A staged in LDS ----------------
template <int KDIM, int NCOLS, bool STATS, bool BNA>
__global__ __launch_bounds__(512) void k_gemm_v12(
    const unsigned short* __restrict__ A, const unsigned short* __restrict__ Wp,
    const float* __restrict__ bias, const float* __restrict__ bnsc, const float* __restrict__ bnsh,
    unsigned short* __restrict__ C, float* __restrict__ Ps, float* __restrict__ Pq) {
  constexpr int CPW = NCOLS / 128;
  constexpr int KS = KDIM / 32;
  constexpr int LDA = KDIM + 8;
  constexpr int NU4 = KDIM / 32;
  __shared__ unsigned short S[128 * LDA];
  __shared__ float sc[BNA ? KDIM : 1], sh[BNA ? KDIM : 1];
  const int t = threadIdx.x;
  const int lane = t & 63, w = t >> 6, fr = lane & 15, fq = lane >> 4;
  const int row0 = blockIdx.x * 128;
  if (BNA) {
    if (t < KDIM) { sc[t] = bnsc[t]; sh[t] = bnsh[t]; }
    __syncthreads();
  }
  bf16x8 B[CPW][KS];
  #pragma unroll
  for (int c = 0; c < CPW; c++)
    #pragma unroll
    for (int s = 0; s < KS; s++)
      B[c][s] = *(const bf16x8*)(Wp + ((size_t)(s * (NCOLS / 16) + (w * CPW + c)) * 64 + lane) * 8);
  {
    int r = t >> 2, q = t & 3;
    int row = row0 + r;
    uint4* dst = (uint4*)(S + r * LDA + q * (KDIM / 4));
    if (row < NN) {
      const uint4* src = (const uint4*)(A + (size_t)row * KDIM + q * (KDIM / 4));
      #pragma unroll
      for (int i = 0; i < NU4; i++) {
        uint4 v = src[i];
        if (BNA) {
          unsigned int u[4] = {v.x, v.y, v.z, v.w};
          #pragma unroll
          for (int p = 0; p < 4; p++) {
            int colb = q * (KDIM / 4) + i * 8 + p * 2;
            float lo = fmaxf(bf2f((unsigned short)(u[p] & 0xFFFF)) * sc[colb] + sh[colb], 0.f);
            float hi = fmaxf(bf2f((unsigned short)(u[p] >> 16)) * sc[colb + 1] + sh[colb + 1], 0.f);
            u[p] = (unsigned int)f2bf(lo) | ((unsigned int)f2bf(hi) << 16);
          }
          v = make_uint4(u[0], u[1], u[2], u[3]);
        }
        dst[i] = v;
      }
    } else {
      #pragma unroll
      for (int i = 0; i < NU4; i++) dst[i] = make_uint4(0, 0, 0, 0);
    }
  }
  __syncthreads();
  f32x4 acc[8][CPW] = {};
  #pragma unroll
  for (int r = 0; r < 8; r++) {
    #pragma unroll
    for (int s = 0; s < KS; s++) {
      bf16x8 a = *(const bf16x8*)(S + (r * 16 + fr) * LDA + s * 32 + fq * 8);
      #pragma unroll
      for (int c = 0; c < CPW; c++)
        acc[r][c] = __builtin_amdgcn_mfma_f32_16x16x32_bf16(a, B[c][s], acc[r][c], 0, 0, 0);
    }
  }
  #pragma unroll
  for (int c = 0; c < CPW; c++) {
    const int col = w * (16 * CPW) + c * 16 + fr;
    float bj = bias[col];
    float s_ = 0.f, q_ = 0.f;
    #pragma unroll
    for (int r = 0; r < 8; r++) {
      #pragma unroll
      for (int rr = 0; rr < 4; rr++) {
        int row = row0 + r * 16 + fq * 4 + rr;
        if (row < NN) {
          float cv = acc[r][c][rr] + bj;
          C[(size_t)row * NCOLS + col] = f2bf(cv);
          if (STATS) { s_ += cv; q_ += cv * cv; }
        }
      }
    }
    if (STATS) {
      s_ += __shfl_xor(s_, 16); q_ += __shfl_xor(q_, 16);
      s_ += __shfl_xor(s_, 32); q_ += __shfl_xor(q_, 32);
      if (fq == 0) {
        Ps[(size_t)blockIdx.x * 256 + col] = s_;
        Pq[(size_t)blockIdx.x * 256 + col] = q_;
      }
    }
  }
}

// ---------------- reduce block partials -> scale/shift ----------------
__global__ __launch_bounds__(256) void k_bnred(const float* __restrict__ Ps, const float* __restrict__ Pq,
                                               const float* __restrict__ g, const float* __restrict__ be,
                                               float* __restrict__ scale, float* __restrict__ shift, int np) {
  __shared__ float Ss[256], Sq[256];
  const int f = blockIdx.x;
  const int t = threadIdx.x;
  float s = 0.f, q = 0.f;
  for (int p = t; p < np; p += 256) { s += Ps[(size_t)p * 256 + f]; q += Pq[(size_t)p * 256 + f]; }
  Ss[t] = s; Sq[t] = q;
  __syncthreads();
  for (int o = 128; o > 0; o >>= 1) { if (t < o) { Ss[t] += Ss[t + o]; Sq[t] += Sq[t + o]; } __syncthreads(); }
  if (t == 0) {
    float m = Ss[0] * (1.f / NN);
    float v = Sq[0] * (1.f / NN) - m * m;
    float sc = g[f] * rsqrtf(v + 1e-5f);
    scale[f] = sc; shift[f] = be[f] - m * sc;
  }
}

// ---------------- aggregation v5: half-wave per node, packed edge meta ----------------
template <int FPL>
__device__ __forceinline__ void ldF(const unsigned short* p, float* f) {
  if constexpr (FPL == 8) {
    uint4 v = *(const uint4*)p;
    unsigned int u[4] = {v.x, v.y, v.z, v.w};
    #pragma unroll
    for (int i = 0; i < 4; i++) {
      f[2 * i] = bf2f((unsigned short)(u[i] & 0xFFFF));
      f[2 * i + 1] = bf2f((unsigned short)(u[i] >> 16));
    }
  } else {
    ushort4 v = *(const ushort4*)p;
    f[0] = bf2f(v.x); f[1] = bf2f(v.y); f[2] = bf2f(v.z); f[3] = bf2f(v.w);
  }
}
template <bool BN, int F>
__global__ __launch_bounds__(256) void k_agg5(const unsigned short* __restrict__ hb,
    const unsigned long long* __restrict__ edg,
    const int* __restrict__ rowptr, const float* __restrict__ dinv,
    const float* __restrict__ scale, const float* __restrict__ shift,
    const float* __restrict__ bias, unsigned short* __restrict__ outb) {
  constexpr int FPL = F / 32;
  const int lane = threadIdx.x & 63;
  const int lg = lane & 31;
  const int srcbase = lane & 32;
  const int n = blockIdx.x * 8 + (threadIdx.x >> 5);
  const int f0 = lg * FPL;
  float sc8[FPL] = {}, sh8[FPL] = {};
  if constexpr (BN) {
    #pragma unroll
    for (int j = 0; j < FPL; j++) { sc8[j] = scale[f0 + j]; sh8[j] = shift[f0 + j]; }
  }
  auto xf = [&](float v, int j) -> float {
    if constexpr (BN) return fmaxf(v * sc8[j] + sh8[j], 0.f);
    else return v;
  };
  float d = dinv[n]; float dd = d * d;
  float acc[FPL];
  {
    float sv[FPL];
    ldF<FPL>(hb + (size_t)n * F + f0, sv);
    #pragma unroll
    for (int j = 0; j < FPL; j++) acc[j] = xf(sv[j], j) * dd + (BN ? 0.f : bias[f0 + j]);
  }
  const int i0 = rowptr[n];
  const int dg = rowptr[n + 1] - i0;
  int sreg = 0; float wreg = 0.f;
  if (lg < dg) unpk(edg[i0 + lg], sreg, wreg);
  const int m = (dg < 32) ? dg : 32;
  int e = 0;
  for (; e + 4 <= m; e += 4) {
    int s0 = __shfl(sreg, srcbase | e), s1 = __shfl(sreg, srcbase | (e + 1));
    int s2 = __shfl(sreg, srcbase | (e + 2)), s3 = __shfl(sreg, srcbase | (e + 3));
    float w0 = __shfl(wreg, srcbase | e), w1 = __shfl(wreg, srcbase | (e + 1));
    float w2 = __shfl(wreg, srcbase | (e + 2)), w3 = __shfl(wreg, srcbase | (e + 3));
    float r0[FPL], r1[FPL], r2[FPL], r3[FPL];
    ldF<FPL>(hb + (size_t)s0 * F + f0, r0);
    ldF<FPL>(hb + (size_t)s1 * F + f0, r1);
    ldF<FPL>(hb + (size_t)s2 * F + f0, r2);
    ldF<FPL>(hb + (size_t)s3 * F + f0, r3);
    #pragma unroll
    for (int j = 0; j < FPL; j++)
      acc[j] += w0 * xf(r0[j], j) + w1 * xf(r1[j], j) + w2 * xf(r2[j], j) + w3 * xf(r3[j], j);
  }
  for (; e < m; e++) {
    int s0 = __shfl(sreg, srcbase | e); float w0 = __shfl(wreg, srcbase | e);
    float r0[FPL];
    ldF<FPL>(hb + (size_t)s0 * F + f0, r0);
    #pragma unroll
    for (int j = 0; j < FPL; j++) acc[j] += w0 * xf(r0[j], j);
  }
  for (int i = i0 + 32; i < i0 + dg; i++) {
    int s0; float w0; unpk(edg[i], s0, w0);
    float r0[FPL];
    ldF<FPL>(hb + (size_t)s0 * F + f0, r0);
    #pragma unroll
    for (int j = 0; j < FPL; j++) acc[j] += w0 * xf(r0[j], j);
  }
  if constexpr (FPL == 8) {
    unsigned int o[4];
    #pragma unroll
    for (int i = 0; i < 4; i++)
      o[i] = (unsigned int)f2bf(acc[2 * i]) | ((unsigned int)f2bf(acc[2 * i + 1]) << 16);
    *(uint4*)(outb + (size_t)n * F + f0) = make_uint4(o[0], o[1], o[2], o[3]);
  } else {
    ushort4 o; o.x = f2bf(acc[0]); o.y = f2bf(acc[1]); o.z = f2bf(acc[2]); o.w = f2bf(acc[3]);
    *(ushort4*)(outb + (size_t)n * F + f0) = o;
  }
}

// ---------------- fused decoder ----------------
__global__ __launch_bounds__(256) void k_decoder3(
    const unsigned short* __restrict__ uv,
    const int* __restrict__ l0, const int* __restrict__ l1,
    const unsigned short* __restrict__ W2p, const float* __restrict__ D2b,
    const float* __restrict__ D3W, const float* __restrict__ D3b,
    float* __restrict__ out) {
  __shared__ unsigned short S[128 * 136];
  __shared__ int ei0[128], ei1[128];
  const int t = threadIdx.x;
  const int base = blockIdx.x * 128;
  if (t < 128) ei0[t] = l0[base + t];
  else ei1[t - 128] = l1[base + t - 128];
  __syncthreads();
  {
    int e = t >> 1, h = t & 1;
    const uint4* pu = (const uint4*)(uv + (size_t)ei0[e] * 256 + h * 64);
    const uint4* pv = (const uint4*)(uv + (size_t)ei1[e] * 256 + 128 + h * 64);
    uint4* dst = (uint4*)(S + e * 136 + h * 64);
    #pragma unroll
    for (int i = 0; i < 8; i++) {
      uint4 a = pu[i], b = pv[i];
      unsigned int ia[4] = {a.x, a.y, a.z, a.w};
      unsigned int ib[4] = {b.x, b.y, b.z, b.w};
      unsigned int o[4];
      #pragma unroll
      for (int p = 0; p < 4; p++) {
        float lo = fmaxf(bf2f((unsigned short)(ia[p] & 0xFFFF)) + bf2f((unsigned short)(ib[p] & 0xFFFF)), 0.f);
        float hi = fmaxf(bf2f((unsigned short)(ia[p] >> 16)) + bf2f((unsigned short)(ib[p] >> 16)), 0.f);
        o[p] = (unsigned int)f2bf(lo) | ((unsigned int)f2bf(hi) << 16);
      }
      dst[i] = make_uint4(o[0], o[1], o[2], o[3]);
    }
  }
  __syncthreads();
  const int lane = t & 63, w = t >> 6, fr = lane & 15, fq = lane >> 4;
  f32x4 acc2[2][8] = {};
  #pragma unroll
  for (int s = 0; s < 4; s++) {
    bf16x8 a0 = *(const bf16x8*)(S + (w * 32 + fr) * 136 + s * 32 + fq * 8);
    bf16x8 a1 = *(const bf16x8*)(S + (w * 32 + 16 + fr) * 136 + s * 32 + fq * 8);
    #pragma unroll
    for (int j = 0; j < 8; j++) {
      bf16x8 bw = *(const bf16x8*)(W2p + ((size_t)(s * 8 + j) * 64 + lane) * 8);
      acc2[0][j] = __builtin_amdgcn_mfma_f32_16x16x32_bf16(a0, bw, acc2[0][j], 0, 0, 0);
      acc2[1][j] = __builtin_amdgcn_mfma_f32_16x16x32_bf16(a1, bw, acc2[1][j], 0, 0, 0);
    }
  }
  float b2v[8], w3v[8];
  #pragma unroll
  for (int j = 0; j < 8; j++) { b2v[j] = D2b[j * 16 + fr]; w3v[j] = D3W[j * 16 + fr]; }
  float d3b = D3b[0];
  #pragma unroll
  for (int f = 0; f < 2; f++) {
    float p[4] = {0.f, 0.f, 0.f, 0.f};
    #pragma unroll
    for (int j = 0; j < 8; j++)
      #pragma unroll
      for (int r = 0; r < 4; r++)
        p[r] += fmaxf(acc2[f][j][r] + b2v[j], 0.f) * w3v[j];
    #pragma unroll
    for (int r = 0; r < 4; r++) {
      p[r] += __shfl_xor(p[r], 1);
      p[r] += __shfl_xor(p[r], 2);
      p[r] += __shfl_xor(p[r], 4);
      p[r] += __shfl_xor(p[r], 8);
      if (fr == 0) out[base + w * 32 + f * 16 + fq * 4 + r] = 1.f / (1.f + expf(-(p[r] + d3b)));
    }
  }
}

// ---------------- host ----------------
extern "C" void kernel_launch(void* const* d_in, const int* in_sizes, int n_in,
                              void* d_out, int out_size, void* d_ws, size_t ws_size,
                              hipStream_t stream) {
  const float* x = (const float*)d_in[0];
  const int* ei = (const int*)d_in[1];
  const int* esrc = ei; const int* edst = ei + NE;
  const float* ew = (const float*)d_in[2];
  const int* eli = (const int*)d_in[3];
  const int* l0 = eli; const int* l1 = eli + NL;
  const float* W1 = (const float*)d_in[4],  *b1 = (const float*)d_in[5];
  const float* g1 = (const float*)d_in[6],  *be1 = (const float*)d_in[7];
  const float* W2 = (const float*)d_in[8],  *b2 = (const float*)d_in[9];
  const float* g2 = (const float*)d_in[10], *be2 = (const float*)d_in[11];
  const float* W3 = (const float*)d_in[12], *b3 = (const float*)d_in[13];
  const float* g3 = (const float*)d_in[14], *be3 = (const float*)d_in[15];
  const float* W4 = (const float*)d_in[16], *b4 = (const float*)d_in[17];
  const float* D1W = (const float*)d_in[18], *D1b = (const float*)d_in[19];
  const float* D2W = (const float*)d_in[20], *D2b = (const float*)d_in[21];
  const float* D3W = (const float*)d_in[22], *D3b = (const float*)d_in[23];
  float* out = (float*)d_out;

  float* wf = (float*)d_ws;
  size_t off = 0;
  auto A = [&](size_t n) { float* p = wf + off; off += (n + 63) & ~(size_t)63; return p; };
  float* dinv = A(NN);
  float* scale = A(256);
  float* shift = A(256);
  float* buv = A(256);
  float* zero128 = A(128);
  float* Ps = A((size_t)NP1 * 256);
  float* Pq = A((size_t)NP1 * 256);
  float* axf = A((size_t)NN * 16);
  unsigned long long* dc = (unsigned long long*)A(2 * (size_t)NN);
  unsigned long long* edg = (unsigned long long*)A(2 * (size_t)NE);
  int* cnt = (int*)A(NN);
  int* rowptr = (int*)A(NN + 1);
  int* nxt = (int*)A(NN);
  int* tsum = (int*)A(256);
  int* toff = (int*)A(256);
  unsigned short* hbA = (unsigned short*)A((size_t)NN * 128);
  unsigned short* hbB = (unsigned short*)A((size_t)NN * 128);
  unsigned short* uv  = (unsigned short*)A((size_t)NN * 128);
  unsigned short* wt2 = (unsigned short*)A(256 * 128);
  unsigned short* wt3 = (unsigned short*)A(256 * 128);
  unsigned short* wt4 = (unsigned short*)A(128 * 128);
  unsigned short* wtD1 = (unsigned short*)A(128 * 128);
  unsigned short* w2t = (unsigned short*)A(64 * 128);
  unsigned short* wp2 = (unsigned short*)A(256 * 128);
  unsigned short* wp3 = (unsigned short*)A(256 * 128);
  unsigned short* wp4 = (unsigned short*)A(128 * 128);
  unsigned short* wpD1 = (unsigned short*)A(128 * 128);
  unsigned short* w2p = (unsigned short*)A(64 * 128);

  const int EB = (NE + 255) / 256;
  const int NB = (NN + 255) / 256;
  const int ST = (NN + 1023) / 1024;
  const int AB = NN / 8;
  const int AG16 = (NN + 63) / 64;

  // graph prep
  hipMemsetAsync(dc, 0, (size_t)NN * 8, stream);
  hipMemsetAsync(zero128, 0, 128 * sizeof(float), stream);
  k_degcnt<<<EB, 256, 0, stream>>>(edst, ew, dc);
  k_dinv2<<<NB, 256, 0, stream>>>(dc, dinv, cnt);
  k_scan1<<<ST, 256, 0, stream>>>(cnt, tsum);
  k_scan2<<<1, 256, 0, stream>>>(tsum, toff, ST, rowptr + NN);
  k_scan3<<<ST, 256, 0, stream>>>(cnt, toff, rowptr, nxt);
  k_scatter2<<<EB, 256, 0, stream>>>(esrc, edst, ew, dinv, nxt, edg);

  // weight conversions + fragment packing
  k_cvt_wT<<<(256 * 256 + 255) / 256, 256, 0, stream>>>(W2, wt2, 256, 256);
  k_cvt_wT<<<(256 * 256 + 255) / 256, 256, 0, stream>>>(W3, wt3, 256, 256);
  k_cvt_wT<<<(256 * 128 + 255) / 256, 256, 0, stream>>>(W4, wt4, 256, 128);
  k_cvt_d1<<<(256 * 128 + 255) / 256, 256, 0, stream>>>(D1W, wtD1);
  k_cvt_wT<<<(128 * 128 + 255) / 256, 256, 0, stream>>>(D2W, w2t, 128, 128);
  k_biasuv<<<1, 256, 0, stream>>>(D1b, buv);
  k_pack<<<32, 256, 0, stream>>>(wt2, wp2, 256, 16);
  k_pack<<<32, 256, 0, stream>>>(wt3, wp3, 256, 16);
  k_pack<<<16, 256, 0, stream>>>(wt4, wp4, 256, 8);
  k_pack<<<16, 256, 0, stream>>>(wtD1, wpD1, 128, 16);
  k_pack<<<8, 256, 0, stream>>>(w2t, w2p, 128, 8);

  // layer 1: ax = agg(x) [fp32,16] ; h1 = ax@W1 + b1 (+stats)
  k_agg16<<<AG16, 256, 0, stream>>>(x, edg, rowptr, dinv, axf);
  k_gemm16s<<<NP1, 256, 0, stream>>>(axf, W1, b1, hbB, Ps, Pq);
  k_bnred<<<256, 256, 0, stream>>>(Ps, Pq, g1, be1, scale, shift, NP1);

  // layer 2: g1 = agg(relu(BN1(h1))) ; h2 = g1@W2 + b2 (+stats)
  k_agg5<true, 256><<<AB, 256, 0, stream>>>(hbB, edg, rowptr, dinv, scale, shift, nullptr, hbA);
  k_gemm_v12<256, 256, true, false><<<GB, 512, 0, stream>>>(hbA, wp2, b2, nullptr, nullptr, hbB, Ps, Pq);
  k_bnred<<<256, 256, 0, stream>>>(Ps, Pq, g2, be2, scale, shift, GB);

  // layer 3
  k_agg5<true, 256><<<AB, 256, 0, stream>>>(hbB, edg, rowptr, dinv, scale, shift, nullptr, hbA);
  k_gemm_v12<256, 256, true, false><<<GB, 512, 0, stream>>>(hbA, wp3, b3, nullptr, nullptr, hbB, Ps, Pq);
  k_bnred<<<256, 256, 0, stream>>>(Ps, Pq, g3, be3, scale, shift, GB);

  // layer 4 (narrowed): t = relu(BN3(h3))@W4 [bf16,128] ; z = agg(t)+b4 ; uv = z@[D1Wu|D1Wv]+buv
  k_gemm_v12<256, 128, false, true><<<GB, 512, 0, stream>>>(hbB, wp4, zero128, scale, shift, hbA, nullptr, nullptr);
  k_agg5<false, 128><<<AB, 256, 0, stream>>>(hbA, edg, rowptr, dinv, nullptr, nullptr, b4, hbB);
  k_gemm_v12<128, 256, false, false><<<GB, 512, 0, stream>>>(hbB, wpD1, buv, nullptr, nullptr, uv, nullptr, nullptr);

  // decoder layers 2-3
  k_decoder3<<<NL / 128, 256, 0, stream>>>(uv, l0, l1, w2p, D2b, D3W, D3b, out);
}

// Round 17
// 592.291 us; speedup vs baseline: 1.1595x; 1.0253x over previous
//
#include <hip/hip_runtime.h>
#include <cmath>

#define NN 100000
#define NE 800000
#define NL 262144
#define GB 782    // ceil(NN/128): 256-col gemm blocks
#define NP1 3125  // ceil(NN/32): gemm16s blocks

typedef __attribute__((ext_vector_type(8))) short bf16x8;
typedef __attribute__((ext_vector_type(4))) float f32x4;

__device__ __forceinline__ unsigned short f2bf(float f) {
  unsigned int u = __builtin_bit_cast(unsigned int, f);
  u = (u + 0x7FFF + ((u >> 16) & 1)) >> 16;
  return (unsigned short)u;
}
__device__ __forceinline__ float bf2f(unsigned short u) {
  return __builtin_bit_cast(float, (unsigned int)u << 16);
}
__device__ __forceinline__ void unpk(unsigned long long v, int& s, float& w) {
  s = (int)(unsigned int)v;
  w = __builtin_bit_cast(float, (unsigned int)(v >> 32));
}

// ---------------- graph prep ----------------
__global__ void k_degcnt(const int* __restrict__ dst, const float* __restrict__ w,
                         unsigned long long* __restrict__ dc) {
  int e = blockIdx.x * 256 + threadIdx.x;
  if (e < NE) {
    unsigned long long pk = (1ULL << 32) | (unsigned long long)(unsigned int)(w[e] * 8388608.0f);
    atomicAdd(&dc[dst[e]], pk);
  }
}
__global__ void k_dinv2(const unsigned long long* __restrict__ dc,
                        float* __restrict__ dinv, int* __restrict__ cnt) {
  int n = blockIdx.x * 256 + threadIdx.x;
  if (n < NN) {
    unsigned long long v = dc[n];
    cnt[n] = (int)(v >> 32);
    dinv[n] = rsqrtf((float)(unsigned int)v * (1.0f / 8388608.0f) + 1.0f);
  }
}
__global__ void k_scan1(const int* __restrict__ cnt, int* __restrict__ tsum) {
  __shared__ int s[256];
  int t = threadIdx.x;
  int base = blockIdx.x * 1024;
  int acc = 0;
  for (int i = 0; i < 4; i++) { int idx = base + t * 4 + i; if (idx < NN) acc += cnt[idx]; }
  s[t] = acc; __syncthreads();
  for (int o = 128; o > 0; o >>= 1) { if (t < o) s[t] += s[t + o]; __syncthreads(); }
  if (t == 0) tsum[blockIdx.x] = s[0];
}
__global__ void k_scan2(const int* __restrict__ tsum, int* __restrict__ toff, int nt, int* __restrict__ rowptr_end) {
  __shared__ int s[256];
  int t = threadIdx.x;
  int v = (t < nt) ? tsum[t] : 0;
  s[t] = v; __syncthreads();
  for (int o = 1; o < 256; o <<= 1) { int xv = (t >= o) ? s[t - o] : 0; __syncthreads(); s[t] += xv; __syncthreads(); }
  if (t < nt) toff[t] = s[t] - v;
  if (t == 255) *rowptr_end = s[255];
}
__global__ void k_scan3(const int* __restrict__ cnt, const int* __restrict__ toff,
                        int* __restrict__ rowptr, int* __restrict__ nxt) {
  __shared__ int s[256];
  int t = threadIdx.x;
  int base = blockIdx.x * 1024 + t * 4;
  int v[4]; int tot = 0;
  for (int i = 0; i < 4; i++) { int idx = base + i; v[i] = (idx < NN) ? cnt[idx] : 0; tot += v[i]; }
  s[t] = tot; __syncthreads();
  for (int o = 1; o < 256; o <<= 1) { int xv = (t >= o) ? s[t - o] : 0; __syncthreads(); s[t] += xv; __syncthreads(); }
  int excl = s[t] - tot + toff[blockIdx.x];
  for (int i = 0; i < 4; i++) {
    int idx = base + i;
    if (idx < NN) { rowptr[idx] = excl; nxt[idx] = excl; }
    excl += v[i];
  }
}
__global__ void k_scatter2(const int* __restrict__ src, const int* __restrict__ dst, const float* __restrict__ w,
                           const float* __restrict__ dinv, int* __restrict__ nxt,
                           unsigned long long* __restrict__ edg) {
  int e = blockIdx.x * 256 + threadIdx.x;
  if (e < NE) {
    int d = dst[e], s = src[e];
    int p = atomicAdd(&nxt[d], 1);
    float en = dinv[s] * w[e] * dinv[d];
    edg[p] = ((unsigned long long)__builtin_bit_cast(unsigned int, en) << 32) | (unsigned int)s;
  }
}

// ---------------- weight convert/transpose ----------------
__global__ void k_cvt_wT(const float* __restrict__ W, unsigned short* __restrict__ Wt, int K, int N) {
  int id = blockIdx.x * 256 + threadIdx.x;
  if (id >= K * N) return;
  int n = id / K, k = id - n * K;
  Wt[id] = f2bf(W[k * N + n]);
}
__global__ void k_cvt_d1(const float* __restrict__ D1W, unsigned short* __restrict__ Wt) {
  int id = blockIdx.x * 256 + threadIdx.x;
  if (id >= 256 * 128) return;
  int n = id >> 7, k = id & 127;
  float v = (n < 128) ? D1W[(size_t)k * 128 + n] : D1W[(size_t)(128 + k) * 128 + (n - 128)];
  Wt[id] = f2bf(v);
}
__global__ void k_biasuv(const float* __restrict__ D1b, float* __restrict__ buv) {
  int t = threadIdx.x;
  buv[t] = (t < 128) ? D1b[t] : 0.f;
}

// ---------------- fragment-pack ----------------
__global__ void k_pack(const unsigned short* __restrict__ Wt, unsigned short* __restrict__ P, int K, int NJ) {
  int id = blockIdx.x * 256 + threadIdx.x;
  int total = (K / 32) * NJ * 64;
  if (id >= total) return;
  int lane = id & 63, g = id >> 6;
  int j = g % NJ, s = g / NJ;
  int fr = lane & 15, fq = lane >> 4;
  uint4 v = *(const uint4*)(Wt + (size_t)(j * 16 + fr) * K + s * 32 + fq * 8);
  *(uint4*)(P + (size_t)id * 8) = v;
}

// ---------------- layer-1 agg on raw x ----------------
__global__ __launch_bounds__(256) void k_agg16(const float* __restrict__ x,
    const unsigned long long* __restrict__ edg,
    const int* __restrict__ rowptr, const float* __restrict__ dinv,
    float* __restrict__ ax) {
  const int t = threadIdx.x;
  const int lane = t & 63;
  const int g = lane >> 2, gl = lane & 3;
  const int n = blockIdx.x * 64 + (t >> 6) * 16 + g;
  if (n >= NN) return;
  const float4* x4 = (const float4*)x;
  float d = dinv[n]; float dd = d * d;
  float4 self = x4[(size_t)n * 4 + gl];
  float4 acc = make_float4(self.x * dd, self.y * dd, self.z * dd, self.w * dd);
  const int i0 = rowptr[n];
  const int dg = rowptr[n + 1] - i0;
  int sreg[4]; float wreg[4];
  #pragma unroll
  for (int k = 0; k < 4; k++) {
    int idx = gl + 4 * k;
    if (idx < dg) unpk(edg[i0 + idx], sreg[k], wreg[k]);
    else { sreg[k] = 0; wreg[k] = 0.f; }
  }
  const int gbase = lane & ~3;
  const int m4 = ((dg < 16 ? dg : 16) + 3) & ~3;
  #pragma unroll 4
  for (int e = 0; e < m4; e += 4) {
    int k = e >> 2;
    int s0, s1, s2, s3; float w0, w1, w2, w3;
    switch (k) {
      case 0: s0=__shfl(sreg[0],gbase|0); s1=__shfl(sreg[0],gbase|1); s2=__shfl(sreg[0],gbase|2); s3=__shfl(sreg[0],gbase|3);
              w0=__shfl(wreg[0],gbase|0); w1=__shfl(wreg[0],gbase|1); w2=__shfl(wreg[0],gbase|2); w3=__shfl(wreg[0],gbase|3); break;
      case 1: s0=__shfl(sreg[1],gbase|0); s1=__shfl(sreg[1],gbase|1); s2=__shfl(sreg[1],gbase|2); s3=__shfl(sreg[1],gbase|3);
              w0=__shfl(wreg[1],gbase|0); w1=__shfl(wreg[1],gbase|1); w2=__shfl(wreg[1],gbase|2); w3=__shfl(wreg[1],gbase|3); break;
      case 2: s0=__shfl(sreg[2],gbase|0); s1=__shfl(sreg[2],gbase|1); s2=__shfl(sreg[2],gbase|2); s3=__shfl(sreg[2],gbase|3);
              w0=__shfl(wreg[2],gbase|0); w1=__shfl(wreg[2],gbase|1); w2=__shfl(wreg[2],gbase|2); w3=__shfl(wreg[2],gbase|3); break;
      default: s0=__shfl(sreg[3],gbase|0); s1=__shfl(sreg[3],gbase|1); s2=__shfl(sreg[3],gbase|2); s3=__shfl(sreg[3],gbase|3);
              w0=__shfl(wreg[3],gbase|0); w1=__shfl(wreg[3],gbase|1); w2=__shfl(wreg[3],gbase|2); w3=__shfl(wreg[3],gbase|3); break;
    }
    float4 r0 = x4[(size_t)s0 * 4 + gl], r1 = x4[(size_t)s1 * 4 + gl];
    float4 r2 = x4[(size_t)s2 * 4 + gl], r3 = x4[(size_t)s3 * 4 + gl];
    acc.x += w0 * r0.x + w1 * r1.x + w2 * r2.x + w3 * r3.x;
    acc.y += w0 * r0.y + w1 * r1.y + w2 * r2.y + w3 * r3.y;
    acc.z += w0 * r0.z + w1 * r1.z + w2 * r2.z + w3 * r3.z;
    acc.w += w0 * r0.w + w1 * r1.w + w2 * r2.w + w3 * r3.w;
  }
  for (int i = i0 + 16; i < i0 + dg; i++) {
    int s0; float w0; unpk(edg[i], s0, w0);
    float4 r0 = x4[(size_t)s0 * 4 + gl];
    acc.x += w0 * r0.x; acc.y += w0 * r0.y; acc.z += w0 * r0.z; acc.w += w0 * r0.w;
  }
  ((float4*)ax)[(size_t)n * 4 + gl] = acc;
}

// ---------------- layer-1 GEMM ----------------
__global__ __launch_bounds__(256) void k_gemm16s(const float* __restrict__ ax, const float* __restrict__ W,
                                                 const float* __restrict__ b, unsigned short* __restrict__ out,
                                                 float* __restrict__ Ps, float* __restrict__ Pq) {
  __shared__ float xs[32][17];
  int t = threadIdx.x; int row0 = blockIdx.x * 32;
  for (int i = t; i < 512; i += 256) {
    int r = i >> 4, c = i & 15; int row = row0 + r;
    xs[r][c] = (row < NN) ? ax[(size_t)row * 16 + c] : 0.f;
  }
  float w[16];
  #pragma unroll
  for (int k = 0; k < 16; k++) w[k] = W[k * 256 + t];
  float bt = b[t];
  __syncthreads();
  float s_ = 0.f, q_ = 0.f;
  for (int r = 0; r < 32; r++) {
    int row = row0 + r; if (row >= NN) break;
    float acc = bt;
    #pragma unroll
    for (int k = 0; k < 16; k++) acc += xs[r][k] * w[k];
    out[(size_t)row * 256 + t] = f2bf(acc);
    s_ += acc; q_ += acc * acc;
  }
  Ps[(size_t)blockIdx.x * 256 + t] = s_;
  Pq[(size_t)blockIdx.x * 256 + t] = q_;
}

// ---------------- MFMA GEMM v13: B in registers, A staged in K-chunked LDS (34.8 KB) ----------------
template <int KDIM, int NCOLS, bool STATS, bool BNA>
__global__ __launch_bounds__(512) void k_gemm_v13(
    const unsigned short* __restrict__ A, const unsigned short* __restrict__ Wp,
    const float* __restrict__ bias, const float* __restrict__ bnsc, const float* __restrict__ bnsh,
    unsigned short* __restrict__ C, float* __restrict__ Ps, float* __restrict__ Pq) {
  constexpr int CPW = NCOLS / 128;      // cols-per-wave / 16
  constexpr int KS = KDIM / 32;         // total K steps
  constexpr int CH = KDIM / 128;        // 128-wide K chunks (1 or 2)
  __shared__ unsigned short S[128 * 136];
  __shared__ float sc[BNA ? KDIM : 1], sh[BNA ? KDIM : 1];
  const int t = threadIdx.x;
  const int lane = t & 63, w = t >> 6, fr = lane & 15, fq = lane >> 4;
  const int row0 = blockIdx.x * 128;
  if (BNA) {
    if (t < KDIM) { sc[t] = bnsc[t]; sh[t] = bnsh[t]; }
    __syncthreads();
  }
  bf16x8 B[CPW][KS];
  #pragma unroll
  for (int c = 0; c < CPW; c++)
    #pragma unroll
    for (int s = 0; s < KS; s++)
      B[c][s] = *(const bf16x8*)(Wp + ((size_t)(s * (NCOLS / 16) + (w * CPW + c)) * 64 + lane) * 8);
  f32x4 acc[8][CPW] = {};
  #pragma unroll
  for (int ck = 0; ck < CH; ck++) {
    // stage 128x128 chunk: 4 threads/row, 4 x uint4 each
    {
      int r = t >> 2, q = t & 3;
      int row = row0 + r;
      uint4* dst = (uint4*)(S + r * 136 + q * 32);
      if (row < NN) {
        const uint4* src = (const uint4*)(A + (size_t)row * KDIM + ck * 128 + q * 32);
        #pragma unroll
        for (int i = 0; i < 4; i++) {
          uint4 v = src[i];
          if (BNA) {
            unsigned int u[4] = {v.x, v.y, v.z, v.w};
            #pragma unroll
            for (int p = 0; p < 4; p++) {
              int colb = ck * 128 + q * 32 + i * 8 + p * 2;
              float lo = fmaxf(bf2f((unsigned short)(u[p] & 0xFFFF)) * sc[colb] + sh[colb], 0.f);
              float hi = fmaxf(bf2f((unsigned short)(u[p] >> 16)) * sc[colb + 1] + sh[colb + 1], 0.f);
              u[p] = (unsigned int)f2bf(lo) | ((unsigned int)f2bf(hi) << 16);
            }
            v = make_uint4(u[0], u[1], u[2], u[3]);
          }
          dst[i] = v;
        }
      } else {
        #pragma unroll
        for (int i = 0; i < 4; i++) dst[i] = make_uint4(0, 0, 0, 0);
      }
    }
    __syncthreads();
    #pragma unroll
    for (int r = 0; r < 8; r++) {
      #pragma unroll
      for (int s = 0; s < 4; s++) {
        bf16x8 a = *(const bf16x8*)(S + (r * 16 + fr) * 136 + s * 32 + fq * 8);
        #pragma unroll
        for (int c = 0; c < CPW; c++)
          acc[r][c] = __builtin_amdgcn_mfma_f32_16x16x32_bf16(a, B[c][ck * 4 + s], acc[r][c], 0, 0, 0);
      }
    }
    if (ck + 1 < CH) __syncthreads();
  }
  #pragma unroll
  for (int c = 0; c < CPW; c++) {
    const int col = w * (16 * CPW) + c * 16 + fr;
    float bj = bias[col];
    float s_ = 0.f, q_ = 0.f;
    #pragma unroll
    for (int r = 0; r < 8; r++) {
      #pragma unroll
      for (int rr = 0; rr < 4; rr++) {
        int row = row0 + r * 16 + fq * 4 + rr;
        if (row < NN) {
          float cv = acc[r][c][rr] + bj;
          C[(size_t)row * NCOLS + col] = f2bf(cv);
          if (STATS) { s_ += cv; q_ += cv * cv; }
        }
      }
    }
    if (STATS) {
      s_ += __shfl_xor(s_, 16); q_ += __shfl_xor(q_, 16);
      s_ += __shfl_xor(s_, 32); q_ += __shfl_xor(q_, 32);
      if (fq == 0) {
        Ps[(size_t)blockIdx.x * 256 + col] = s_;
        Pq[(size_t)blockIdx.x * 256 + col] = q_;
      }
    }
  }
}

// ---------------- reduce block partials -> scale/shift ----------------
__global__ __launch_bounds__(256) void k_bnred(const float* __restrict__ Ps, const float* __restrict__ Pq,
                                               const float* __restrict__ g, const float* __restrict__ be,
                                               float* __restrict__ scale, float* __restrict__ shift, int np) {
  __shared__ float Ss[256], Sq[256];
  const int f = blockIdx.x;
  const int t = threadIdx.x;
  float s = 0.f, q = 0.f;
  for (int p = t; p < np; p += 256) { s += Ps[(size_t)p * 256 + f]; q += Pq[(size_t)p * 256 + f]; }
  Ss[t] = s; Sq[t] = q;
  __syncthreads();
  for (int o = 128; o > 0; o >>= 1) { if (t < o) { Ss[t] += Ss[t + o]; Sq[t] += Sq[t + o]; } __syncthreads(); }
  if (t == 0) {
    float m = Ss[0] * (1.f / NN);
    float v = Sq[0] * (1.f / NN) - m * m;
    float sc = g[f] * rsqrtf(v + 1e-5f);
    scale[f] = sc; shift[f] = be[f] - m * sc;
  }
}

// ---------------- aggregation v5: half-wave per node, packed edge meta ----------------
template <int FPL>
__device__ __forceinline__ void ldF(const unsigned short* p, float* f) {
  if constexpr (FPL == 8) {
    uint4 v = *(const uint4*)p;
    unsigned int u[4] = {v.x, v.y, v.z, v.w};
    #pragma unroll
    for (int i = 0; i < 4; i++) {
      f[2 * i] = bf2f((unsigned short)(u[i] & 0xFFFF));
      f[2 * i + 1] = bf2f((unsigned short)(u[i] >> 16));
    }
  } else {
    ushort4 v = *(const ushort4*)p;
    f[0] = bf2f(v.x); f[1] = bf2f(v.y); f[2] = bf2f(v.z); f[3] = bf2f(v.w);
  }
}
template <bool BN, int F>
__global__ __launch_bounds__(256) void k_agg5(const unsigned short* __restrict__ hb,
    const unsigned long long* __restrict__ edg,
    const int* __restrict__ rowptr, const float* __restrict__ dinv,
    const float* __restrict__ scale, const float* __restrict__ shift,
    const float* __restrict__ bias, unsigned short* __restrict__ outb) {
  constexpr int FPL = F / 32;
  const int lane = threadIdx.x & 63;
  const int lg = lane & 31;
  const int srcbase = lane & 32;
  const int n = blockIdx.x * 8 + (threadIdx.x >> 5);
  const int f0 = lg * FPL;
  float sc8[FPL] = {}, sh8[FPL] = {};
  if constexpr (BN) {
    #pragma unroll
    for (int j = 0; j < FPL; j++) { sc8[j] = scale[f0 + j]; sh8[j] = shift[f0 + j]; }
  }
  auto xf = [&](float v, int j) -> float {
    if constexpr (BN) return fmaxf(v * sc8[j] + sh8[j], 0.f);
    else return v;
  };
  float d = dinv[n]; float dd = d * d;
  float acc[FPL];
  {
    float sv[FPL];
    ldF<FPL>(hb + (size_t)n * F + f0, sv);
    #pragma unroll
    for (int j = 0; j < FPL; j++) acc[j] = xf(sv[j], j) * dd + (BN ? 0.f : bias[f0 + j]);
  }
  const int i0 = rowptr[n];
  const int dg = rowptr[n + 1] - i0;
  int sreg = 0; float wreg = 0.f;
  if (lg < dg) unpk(edg[i0 + lg], sreg, wreg);
  const int m = (dg < 32) ? dg : 32;
  int e = 0;
  for (; e + 4 <= m; e += 4) {
    int s0 = __shfl(sreg, srcbase | e), s1 = __shfl(sreg, srcbase | (e + 1));
    int s2 = __shfl(sreg, srcbase | (e + 2)), s3 = __shfl(sreg, srcbase | (e + 3));
    float w0 = __shfl(wreg, srcbase | e), w1 = __shfl(wreg, srcbase | (e + 1));
    float w2 = __shfl(wreg, srcbase | (e + 2)), w3 = __shfl(wreg, srcbase | (e + 3));
    float r0[FPL], r1[FPL], r2[FPL], r3[FPL];
    ldF<FPL>(hb + (size_t)s0 * F + f0, r0);
    ldF<FPL>(hb + (size_t)s1 * F + f0, r1);
    ldF<FPL>(hb + (size_t)s2 * F + f0, r2);
    ldF<FPL>(hb + (size_t)s3 * F + f0, r3);
    #pragma unroll
    for (int j = 0; j < FPL; j++)
      acc[j] += w0 * xf(r0[j], j) + w1 * xf(r1[j], j) + w2 * xf(r2[j], j) + w3 * xf(r3[j], j);
  }
  for (; e < m; e++) {
    int s0 = __shfl(sreg, srcbase | e); float w0 = __shfl(wreg, srcbase | e);
    float r0[FPL];
    ldF<FPL>(hb + (size_t)s0 * F + f0, r0);
    #pragma unroll
    for (int j = 0; j < FPL; j++) acc[j] += w0 * xf(r0[j], j);
  }
  for (int i = i0 + 32; i < i0 + dg; i++) {
    int s0; float w0; unpk(edg[i], s0, w0);
    float r0[FPL];
    ldF<FPL>(hb + (size_t)s0 * F + f0, r0);
    #pragma unroll
    for (int j = 0; j < FPL; j++) acc[j] += w0 * xf(r0[j], j);
  }
  if constexpr (FPL == 8) {
    unsigned int o[4];
    #pragma unroll
    for (int i = 0; i < 4; i++)
      o[i] = (unsigned int)f2bf(acc[2 * i]) | ((unsigned int)f2bf(acc[2 * i + 1]) << 16);
    *(uint4*)(outb + (size_t)n * F + f0) = make_uint4(o[0], o[1], o[2], o[3]);
  } else {
    ushort4 o; o.x = f2bf(acc[0]); o.y = f2bf(acc[1]); o.z = f2bf(acc[2]); o.w = f2bf(acc[3]);
    *(ushort4*)(outb + (size_t)n * F + f0) = o;
  }
}

// ---------------- fused decoder ----------------
__global__ __launch_bounds__(256) void k_decoder3(
    const unsigned short* __restrict__ uv,
    const int* __restrict__ l0, const int* __restrict__ l1,
    const unsigned short* __restrict__ W2p, const float* __restrict__ D2b,
    const float* __restrict__ D3W, const float* __restrict__ D3b,
    float* __restrict__ out) {
  __shared__ unsigned short S[128 * 136];
  __shared__ int ei0[128], ei1[128];
  const int t = threadIdx.x;
  const int base = blockIdx.x * 128;
  if (t < 128) ei0[t] = l0[base + t];
  else ei1[t - 128] = l1[base + t - 128];
  __syncthreads();
  {
    int e = t >> 1, h = t & 1;
    const uint4* pu = (const uint4*)(uv + (size_t)ei0[e] * 256 + h * 64);
    const uint4* pv = (const uint4*)(uv + (size_t)ei1[e] * 256 + 128 + h * 64);
    uint4* dst = (uint4*)(S + e * 136 + h * 64);
    #pragma unroll
    for (int i = 0; i < 8; i++) {
      uint4 a = pu[i], b = pv[i];
      unsigned int ia[4] = {a.x, a.y, a.z, a.w};
      unsigned int ib[4] = {b.x, b.y, b.z, b.w};
      unsigned int o[4];
      #pragma unroll
      for (int p = 0; p < 4; p++) {
        float lo = fmaxf(bf2f((unsigned short)(ia[p] & 0xFFFF)) + bf2f((unsigned short)(ib[p] & 0xFFFF)), 0.f);
        float hi = fmaxf(bf2f((unsigned short)(ia[p] >> 16)) + bf2f((unsigned short)(ib[p] >> 16)), 0.f);
        o[p] = (unsigned int)f2bf(lo) | ((unsigned int)f2bf(hi) << 16);
      }
      dst[i] = make_uint4(o[0], o[1], o[2], o[3]);
    }
  }
  __syncthreads();
  const int lane = t & 63, w = t >> 6, fr = lane & 15, fq = lane >> 4;
  f32x4 acc2[2][8] = {};
  #pragma unroll
  for (int s = 0; s < 4; s++) {
    bf16x8 a0 = *(const bf16x8*)(S + (w * 32 + fr) * 136 + s * 32 + fq * 8);
    bf16x8 a1 = *(const bf16x8*)(S + (w * 32 + 16 + fr) * 136 + s * 32 + fq * 8);
    #pragma unroll
    for (int j = 0; j < 8; j++) {
      bf16x8 bw = *(const bf16x8*)(W2p + ((size_t)(s * 8 + j) * 64 + lane) * 8);
      acc2[0][j] = __builtin_amdgcn_mfma_f32_16x16x32_bf16(a0, bw, acc2[0][j], 0, 0, 0);
      acc2[1][j] = __builtin_amdgcn_mfma_f32_16x16x32_bf16(a1, bw, acc2[1][j], 0, 0, 0);
    }
  }
  float b2v[8], w3v[8];
  #pragma unroll
  for (int j = 0; j < 8; j++) { b2v[j] = D2b[j * 16 + fr]; w3v[j] = D3W[j * 16 + fr]; }
  float d3b = D3b[0];
  #pragma unroll
  for (int f = 0; f < 2; f++) {
    float p[4] = {0.f, 0.f, 0.f, 0.f};
    #pragma unroll
    for (int j = 0; j < 8; j++)
      #pragma unroll
      for (int r = 0; r < 4; r++)
        p[r] += fmaxf(acc2[f][j][r] + b2v[j], 0.f) * w3v[j];
    #pragma unroll
    for (int r = 0; r < 4; r++) {
      p[r] += __shfl_xor(p[r], 1);
      p[r] += __shfl_xor(p[r], 2);
      p[r] += __shfl_xor(p[r], 4);
      p[r] += __shfl_xor(p[r], 8);
      if (fr == 0) out[base + w * 32 + f * 16 + fq * 4 + r] = 1.f / (1.f + expf(-(p[r] + d3b)));
    }
  }
}

// ---------------- host ----------------
extern "C" void kernel_launch(void* const* d_in, const int* in_sizes, int n_in,
                              void* d_out, int out_size, void* d_ws, size_t ws_size,
                              hipStream_t stream) {
  const float* x = (const float*)d_in[0];
  const int* ei = (const int*)d_in[1];
  const int* esrc = ei; const int* edst = ei + NE;
  const float* ew = (const float*)d_in[2];
  const int* eli = (const int*)d_in[3];
  const int* l0 = eli; const int* l1 = eli + NL;
  const float* W1 = (const float*)d_in[4],  *b1 = (const float*)d_in[5];
  const float* g1 = (const float*)d_in[6],  *be1 = (const float*)d_in[7];
  const float* W2 = (const float*)d_in[8],  *b2 = (const float*)d_in[9];
  const float* g2 = (const float*)d_in[10], *be2 = (const float*)d_in[11];
  const float* W3 = (const float*)d_in[12], *b3 = (const float*)d_in[13];
  const float* g3 = (const float*)d_in[14], *be3 = (const float*)d_in[15];
  const float* W4 = (const float*)d_in[16], *b4 = (const float*)d_in[17];
  const float* D1W = (const float*)d_in[18], *D1b = (const float*)d_in[19];
  const float* D2W = (const float*)d_in[20], *D2b = (const float*)d_in[21];
  const float* D3W = (const float*)d_in[22], *D3b = (const float*)d_in[23];
  float* out = (float*)d_out;

  float* wf = (float*)d_ws;
  size_t off = 0;
  auto A = [&](size_t n) { float* p = wf + off; off += (n + 63) & ~(size_t)63; return p; };
  float* dinv = A(NN);
  float* scale = A(256);
  float* shift = A(256);
  float* buv = A(256);
  float* zero128 = A(128);
  float* Ps = A((size_t)NP1 * 256);
  float* Pq = A((size_t)NP1 * 256);
  float* axf = A((size_t)NN * 16);
  unsigned long long* dc = (unsigned long long*)A(2 * (size_t)NN);
  unsigned long long* edg = (unsigned long long*)A(2 * (size_t)NE);
  int* cnt = (int*)A(NN);
  int* rowptr = (int*)A(NN + 1);
  int* nxt = (int*)A(NN);
  int* tsum = (int*)A(256);
  int* toff = (int*)A(256);
  unsigned short* hbA = (unsigned short*)A((size_t)NN * 128);
  unsigned short* hbB = (unsigned short*)A((size_t)NN * 128);
  unsigned short* uv  = (unsigned short*)A((size_t)NN * 128);
  unsigned short* wt2 = (unsigned short*)A(256 * 128);
  unsigned short* wt3 = (unsigned short*)A(256 * 128);
  unsigned short* wt4 = (unsigned short*)A(128 * 128);
  unsigned short* wtD1 = (unsigned short*)A(128 * 128);
  unsigned short* w2t = (unsigned short*)A(64 * 128);
  unsigned short* wp2 = (unsigned short*)A(256 * 128);
  unsigned short* wp3 = (unsigned short*)A(256 * 128);
  unsigned short* wp4 = (unsigned short*)A(128 * 128);
  unsigned short* wpD1 = (unsigned short*)A(128 * 128);
  unsigned short* w2p = (unsigned short*)A(64 * 128);

  const int EB = (NE + 255) / 256;
  const int NB = (NN + 255) / 256;
  const int ST = (NN + 1023) / 1024;
  const int AB = NN / 8;
  const int AG16 = (NN + 63) / 64;

  // graph prep
  hipMemsetAsync(dc, 0, (size_t)NN * 8, stream);
  hipMemsetAsync(zero128, 0, 128 * sizeof(float), stream);
  k_degcnt<<<EB, 256, 0, stream>>>(edst, ew, dc);
  k_dinv2<<<NB, 256, 0, stream>>>(dc, dinv, cnt);
  k_scan1<<<ST, 256, 0, stream>>>(cnt, tsum);
  k_scan2<<<1, 256, 0, stream>>>(tsum, toff, ST, rowptr + NN);
  k_scan3<<<ST, 256, 0, stream>>>(cnt, toff, rowptr, nxt);
  k_scatter2<<<EB, 256, 0, stream>>>(esrc, edst, ew, dinv, nxt, edg);

  // weight conversions + fragment packing
  k_cvt_wT<<<(256 * 256 + 255) / 256, 256, 0, stream>>>(W2, wt2, 256, 256);
  k_cvt_wT<<<(256 * 256 + 255) / 256, 256, 0, stream>>>(W3, wt3, 256, 256);
  k_cvt_wT<<<(256 * 128 + 255) / 256, 256, 0, stream>>>(W4, wt4, 256, 128);
  k_cvt_d1<<<(256 * 128 + 255) / 256, 256, 0, stream>>>(D1W, wtD1);
  k_cvt_wT<<<(128 * 128 + 255) / 256, 256, 0, stream>>>(D2W, w2t, 128, 128);
  k_biasuv<<<1, 256, 0, stream>>>(D1b, buv);
  k_pack<<<32, 256, 0, stream>>>(wt2, wp2, 256, 16);
  k_pack<<<32, 256, 0, stream>>>(wt3, wp3, 256, 16);
  k_pack<<<16, 256, 0, stream>>>(wt4, wp4, 256, 8);
  k_pack<<<16, 256, 0, stream>>>(wtD1, wpD1, 128, 16);
  k_pack<<<8, 256, 0, stream>>>(w2t, w2p, 128, 8);

  // layer 1: ax = agg(x) [fp32,16] ; h1 = ax@W1 + b1 (+stats)
  k_agg16<<<AG16, 256, 0, stream>>>(x, edg, rowptr, dinv, axf);
  k_gemm16s<<<NP1, 256, 0, stream>>>(axf, W1, b1, hbB, Ps, Pq);
  k_bnred<<<256, 256, 0, stream>>>(Ps, Pq, g1, be1, scale, shift, NP1);

  // layer 2: g1 = agg(relu(BN1(h1))) ; h2 = g1@W2 + b2 (+stats)
  k_agg5<true, 256><<<AB, 256, 0, stream>>>(hbB, edg, rowptr, dinv, scale, shift, nullptr, hbA);
  k_gemm_v13<256, 256, true, false><<<GB, 512, 0, stream>>>(hbA, wp2, b2, nullptr, nullptr, hbB, Ps, Pq);
  k_bnred<<<256, 256, 0, stream>>>(Ps, Pq, g2, be2, scale, shift, GB);

  // layer 3
  k_agg5<true, 256><<<AB, 256, 0, stream>>>(hbB, edg, rowptr, dinv, scale, shift, nullptr, hbA);
  k_gemm_v13<256, 256, true, false><<<GB, 512, 0, stream>>>(hbA, wp3, b3, nullptr, nullptr, hbB, Ps, Pq);
  k_bnred<<<256, 256, 0, stream>>>(Ps, Pq, g3, be3, scale, shift, GB);

  // layer 4 (narrowed): t = relu(BN3(h3))@W4 [bf16,128] ; z = agg(t)+b4 ; uv = z@[D1Wu|D1Wv]+buv
  k_gemm_v13<256, 128, false, true><<<GB, 512, 0, stream>>>(hbB, wp4, zero128, scale, shift, hbA, nullptr, nullptr);
  k_agg5<false, 128><<<AB, 256, 0, stream>>>(hbA, edg, rowptr, dinv, nullptr, nullptr, b4, hbB);
  k_gemm_v13<128, 256, false, false><<<GB, 512, 0, stream>>>(hbB, wpD1, buv, nullptr, nullptr, uv, nullptr, nullptr);

  // decoder layers 2-3
  k_decoder3<<<NL / 128, 256, 0, stream>>>(uv, l0, l1, w2p, D2b, D3W, D3b, out);
}